// Round 3
// baseline (766.950 us; speedup 1.0000x reference)
//
#include <hip/hip_runtime.h>
#include <hip/hip_bf16.h>

#define HH 1024
#define NHEADS 8
#define HDIM 128
#define BB 4
#define TT 2048
#define MROWS (BB*TT)   // 8192

typedef __bf16 bf16;
typedef __bf16 bf16x8 __attribute__((ext_vector_type(8)));
typedef float floatx4 __attribute__((ext_vector_type(4)));

// ---------------- LayerNorm stats: one block per row, writes (mu, rs) ----------------
__global__ __launch_bounds__(256) void lnstat_k(const float* __restrict__ x,
                                                float* __restrict__ stats) {
    int row = blockIdx.x;
    const float4* xr = (const float4*)(x + (size_t)row * HH);
    int t = threadIdx.x;
    float4 v = xr[t];
    float s  = v.x + v.y + v.z + v.w;
    float s2 = v.x * v.x + v.y * v.y + v.z * v.z + v.w * v.w;
#pragma unroll
    for (int off = 32; off > 0; off >>= 1) {
        s  += __shfl_down(s,  off);
        s2 += __shfl_down(s2, off);
    }
    __shared__ float red[8];
    if ((t & 63) == 0) { red[t >> 6] = s; red[(t >> 6) + 4] = s2; }
    __syncthreads();
    if (t == 0) {
        s  = red[0] + red[1] + red[2] + red[3];
        s2 = red[4] + red[5] + red[6] + red[7];
        float mu  = s * (1.f / HH);
        float var = s2 * (1.f / HH) - mu * mu;
        stats[row * 2]     = mu;
        stats[row * 2 + 1] = rsqrtf(var + 1e-5f);
    }
}

// ---------------- GEMM, fused LN on A: C(bf16) = LN(x_f32) * W_f32^T ----------------
// 64x64 tile, BK=32, 4 waves 2x2, each wave 32x32 via 2x2 of 16x16x32 MFMA.
__global__ __launch_bounds__(256) void gemm_ln_f32_k(const float* __restrict__ A,
                                                     const float* __restrict__ stats,
                                                     const float* __restrict__ g,
                                                     const float* __restrict__ be,
                                                     const float* __restrict__ W,
                                                     bf16* __restrict__ C,
                                                     int K, int N) {
    __shared__ __align__(16) bf16 As[64][40];  // +8 pad; row stride 80B (mult of 16)
    __shared__ __align__(16) bf16 Ws[64][40];
    int m0 = blockIdx.x * 64, n0 = blockIdx.y * 64;
    int t = threadIdx.x, lane = t & 63, w = t >> 6;
    int wm = w >> 1, wn = w & 1;
    int sr = t >> 2, sc = (t & 3) * 8;
    int mrow = wm * 32 + (lane & 15), nrow = wn * 32 + (lane & 15);
    int kq = (lane >> 4) * 8;
    int arow = m0 + sr;
    float mu = stats[arow * 2], rs = stats[arow * 2 + 1];
    floatx4 acc[2][2] = {};
    for (int k0 = 0; k0 < K; k0 += 32) {
        __syncthreads();
        float vx[8], vg[8], vb[8], vw[8];
        *(float4*)&vx[0] = *(const float4*)&A[(size_t)arow * K + k0 + sc];
        *(float4*)&vx[4] = *(const float4*)&A[(size_t)arow * K + k0 + sc + 4];
        *(float4*)&vg[0] = *(const float4*)&g[k0 + sc];
        *(float4*)&vg[4] = *(const float4*)&g[k0 + sc + 4];
        *(float4*)&vb[0] = *(const float4*)&be[k0 + sc];
        *(float4*)&vb[4] = *(const float4*)&be[k0 + sc + 4];
        *(float4*)&vw[0] = *(const float4*)&W[(size_t)(n0 + sr) * K + k0 + sc];
        *(float4*)&vw[4] = *(const float4*)&W[(size_t)(n0 + sr) * K + k0 + sc + 4];
        bf16x8 nv, wv;
#pragma unroll
        for (int z = 0; z < 8; z++) {
            nv[z] = (bf16)((vx[z] - mu) * rs * vg[z] + vb[z]);
            wv[z] = (bf16)vw[z];
        }
        *(bf16x8*)&As[sr][sc] = nv;
        *(bf16x8*)&Ws[sr][sc] = wv;
        __syncthreads();
        bf16x8 a0 = *(const bf16x8*)&As[mrow][kq];
        bf16x8 a1 = *(const bf16x8*)&As[mrow + 16][kq];
        bf16x8 b0 = *(const bf16x8*)&Ws[nrow][kq];
        bf16x8 b1 = *(const bf16x8*)&Ws[nrow + 16][kq];
        acc[0][0] = __builtin_amdgcn_mfma_f32_16x16x32_bf16(a0, b0, acc[0][0], 0, 0, 0);
        acc[0][1] = __builtin_amdgcn_mfma_f32_16x16x32_bf16(a0, b1, acc[0][1], 0, 0, 0);
        acc[1][0] = __builtin_amdgcn_mfma_f32_16x16x32_bf16(a1, b0, acc[1][0], 0, 0, 0);
        acc[1][1] = __builtin_amdgcn_mfma_f32_16x16x32_bf16(a1, b1, acc[1][1], 0, 0, 0);
    }
    // C/D layout: col = lane&15, row = (lane>>4)*4 + reg
    int quad = lane >> 4, cl = lane & 15;
#pragma unroll
    for (int i = 0; i < 2; i++)
#pragma unroll
        for (int j = 0; j < 2; j++)
#pragma unroll
            for (int rg = 0; rg < 4; rg++) {
                int gr = m0 + wm * 32 + i * 16 + quad * 4 + rg;
                int gc = n0 + wn * 32 + j * 16 + cl;
                C[(size_t)gr * N + gc] = (bf16)acc[i][j][rg];
            }
}

// ---------------- Final GEMM: out_f32 = A_bf16 * W_f32^T + R_f32 ----------------
__global__ __launch_bounds__(256) void gemm_mixed_k(const bf16* __restrict__ A,
                                                    const float* __restrict__ W,
                                                    const float* __restrict__ R,
                                                    float* __restrict__ C,
                                                    int K, int N) {
    __shared__ __align__(16) bf16 As[64][40];
    __shared__ __align__(16) bf16 Ws[64][40];
    int m0 = blockIdx.x * 64, n0 = blockIdx.y * 64;
    int t = threadIdx.x, lane = t & 63, w = t >> 6;
    int wm = w >> 1, wn = w & 1;
    int sr = t >> 2, sc = (t & 3) * 8;
    int mrow = wm * 32 + (lane & 15), nrow = wn * 32 + (lane & 15);
    int kq = (lane >> 4) * 8;
    floatx4 acc[2][2] = {};
    for (int k0 = 0; k0 < K; k0 += 32) {
        __syncthreads();
        float vw[8];
        *(float4*)&vw[0] = *(const float4*)&W[(size_t)(n0 + sr) * K + k0 + sc];
        *(float4*)&vw[4] = *(const float4*)&W[(size_t)(n0 + sr) * K + k0 + sc + 4];
        bf16x8 wv;
#pragma unroll
        for (int z = 0; z < 8; z++) wv[z] = (bf16)vw[z];
        *(bf16x8*)&As[sr][sc] = *(const bf16x8*)&A[(size_t)(m0 + sr) * K + k0 + sc];
        *(bf16x8*)&Ws[sr][sc] = wv;
        __syncthreads();
        bf16x8 a0 = *(const bf16x8*)&As[mrow][kq];
        bf16x8 a1 = *(const bf16x8*)&As[mrow + 16][kq];
        bf16x8 b0 = *(const bf16x8*)&Ws[nrow][kq];
        bf16x8 b1 = *(const bf16x8*)&Ws[nrow + 16][kq];
        acc[0][0] = __builtin_amdgcn_mfma_f32_16x16x32_bf16(a0, b0, acc[0][0], 0, 0, 0);
        acc[0][1] = __builtin_amdgcn_mfma_f32_16x16x32_bf16(a0, b1, acc[0][1], 0, 0, 0);
        acc[1][0] = __builtin_amdgcn_mfma_f32_16x16x32_bf16(a1, b0, acc[1][0], 0, 0, 0);
        acc[1][1] = __builtin_amdgcn_mfma_f32_16x16x32_bf16(a1, b1, acc[1][1], 0, 0, 0);
    }
    int quad = lane >> 4, cl = lane & 15;
#pragma unroll
    for (int i = 0; i < 2; i++)
#pragma unroll
        for (int j = 0; j < 2; j++)
#pragma unroll
            for (int rg = 0; rg < 4; rg++) {
                int gr = m0 + wm * 32 + i * 16 + quad * 4 + rg;
                int gc = n0 + wn * 32 + j * 16 + cl;
                C[(size_t)gr * N + gc] = acc[i][j][rg] + R[(size_t)gr * N + gc];
            }
}

// ---------------- Flash attention (causal), bf16 in/out, 64-row Q tile ----------------
// O may alias Q: each block writes exactly the Q region only it reads (and stages first).
__global__ __launch_bounds__(256) void attn_k(const bf16* __restrict__ Q,
                                              const bf16* __restrict__ Kg,
                                              const bf16* __restrict__ Vg,
                                              bf16* __restrict__ O) {
    __shared__ __align__(16) bf16 Qs[64][136];
    __shared__ __align__(16) bf16 KVs[128 * 72];   // K tile (stride 136) then V^T (stride 72)
    __shared__ float Ss[64][65];
    __shared__ __align__(16) bf16 Ps[64][72];
    __shared__ __align__(16) float alpha_s[64];
    __shared__ __align__(16) float mrun[64];
    __shared__ __align__(16) float lrun[64];
    __shared__ float pmax[256];
    __shared__ float psum[256];

    int qt = blockIdx.x, h = blockIdx.y, b = blockIdx.z;
    int t = threadIdx.x, lane = t & 63, w = t >> 6;
    int wm = w >> 1, wn = w & 1;
    int quad = lane >> 4, cl = lane & 15, kq = quad * 8;
    size_t rowbase = (size_t)b * TT;
    int q0 = qt * 64;
    size_t hcol = (size_t)h * HDIM;

    for (int e = t; e < 1024; e += 256) {
        int r = e >> 4, c = (e & 15) * 8;
        *(bf16x8*)&Qs[r][c] = *(const bf16x8*)&Q[(rowbase + q0 + r) * HH + hcol + c];
    }
    if (t < 64) { mrun[t] = -1e30f; lrun[t] = 0.f; }

    floatx4 acc[2][4] = {};

    for (int kt = 0; kt <= qt; kt++) {
        __syncthreads();
        for (int e = t; e < 1024; e += 256) {
            int r = e >> 4, c = (e & 15) * 8;
            *(bf16x8*)&KVs[r * 136 + c] =
                *(const bf16x8*)&Kg[(rowbase + (size_t)kt * 64 + r) * HH + hcol + c];
        }
        __syncthreads();
        floatx4 sacc[2][2] = {};
#pragma unroll
        for (int kk = 0; kk < 128; kk += 32) {
            bf16x8 a0 = *(const bf16x8*)&Qs[wm * 32 + cl][kk + kq];
            bf16x8 a1 = *(const bf16x8*)&Qs[wm * 32 + 16 + cl][kk + kq];
            bf16x8 b0 = *(const bf16x8*)&KVs[(wn * 32 + cl) * 136 + kk + kq];
            bf16x8 b1 = *(const bf16x8*)&KVs[(wn * 32 + 16 + cl) * 136 + kk + kq];
            sacc[0][0] = __builtin_amdgcn_mfma_f32_16x16x32_bf16(a0, b0, sacc[0][0], 0, 0, 0);
            sacc[0][1] = __builtin_amdgcn_mfma_f32_16x16x32_bf16(a0, b1, sacc[0][1], 0, 0, 0);
            sacc[1][0] = __builtin_amdgcn_mfma_f32_16x16x32_bf16(a1, b0, sacc[1][0], 0, 0, 0);
            sacc[1][1] = __builtin_amdgcn_mfma_f32_16x16x32_bf16(a1, b1, sacc[1][1], 0, 0, 0);
        }
        const float scale = 0.08838834764831845f;  // 1/sqrt(128)
#pragma unroll
        for (int i = 0; i < 2; i++)
#pragma unroll
            for (int j = 0; j < 2; j++)
#pragma unroll
                for (int rg = 0; rg < 4; rg++) {
                    int sr_ = wm * 32 + i * 16 + quad * 4 + rg;
                    int sc_ = wn * 32 + j * 16 + cl;
                    float sv = sacc[i][j][rg] * scale;
                    if (kt == qt && sc_ > sr_) sv = -1e30f;
                    Ss[sr_][sc_] = sv;
                }
        __syncthreads();
        {
            int rr = t >> 2, seg = t & 3;
            float mx = -1e30f;
#pragma unroll
            for (int c = 0; c < 16; c++) mx = fmaxf(mx, Ss[rr][seg * 16 + c]);
            pmax[rr * 4 + seg] = mx;
        }
        __syncthreads();
        if (t < 64) {
            float mn = fmaxf(fmaxf(pmax[t * 4], pmax[t * 4 + 1]),
                             fmaxf(pmax[t * 4 + 2], pmax[t * 4 + 3]));
            float mo = mrun[t];
            mn = fmaxf(mo, mn);
            float al = __expf(mo - mn);
            alpha_s[t] = al;
            mrun[t] = mn;
            lrun[t] *= al;
        }
        __syncthreads();
        {
            int rr = t >> 2, seg = t & 3;
            float mn = mrun[rr];
            float sm = 0.f;
#pragma unroll
            for (int c = 0; c < 16; c++) {
                float p = __expf(Ss[rr][seg * 16 + c] - mn);
                sm += p;
                Ps[rr][seg * 16 + c] = (bf16)p;
            }
            psum[rr * 4 + seg] = sm;
        }
        __syncthreads();
        if (t < 64) lrun[t] += psum[t * 4] + psum[t * 4 + 1] + psum[t * 4 + 2] + psum[t * 4 + 3];
        for (int e = t; e < 1024; e += 256) {
            int r = e >> 4, c = (e & 15) * 8;
            bf16x8 raw = *(const bf16x8*)&Vg[(rowbase + (size_t)kt * 64 + r) * HH + hcol + c];
#pragma unroll
            for (int z = 0; z < 8; z++) KVs[(c + z) * 72 + r] = raw[z];
        }
        __syncthreads();
#pragma unroll
        for (int i = 0; i < 2; i++) {
            floatx4 al = *(const floatx4*)&alpha_s[wm * 32 + i * 16 + quad * 4];
#pragma unroll
            for (int j = 0; j < 4; j++) acc[i][j] *= al;
        }
#pragma unroll
        for (int kti = 0; kti < 2; kti++) {
            bf16x8 p0 = *(const bf16x8*)&Ps[wm * 32 + cl][kti * 32 + kq];
            bf16x8 p1 = *(const bf16x8*)&Ps[wm * 32 + 16 + cl][kti * 32 + kq];
#pragma unroll
            for (int j = 0; j < 4; j++) {
                bf16x8 vf = *(const bf16x8*)&KVs[(wn * 64 + j * 16 + cl) * 72 + kti * 32 + kq];
                acc[0][j] = __builtin_amdgcn_mfma_f32_16x16x32_bf16(p0, vf, acc[0][j], 0, 0, 0);
                acc[1][j] = __builtin_amdgcn_mfma_f32_16x16x32_bf16(p1, vf, acc[1][j], 0, 0, 0);
            }
        }
    }
    __syncthreads();
    if (t < 64) lrun[t] = 1.f / lrun[t];
    __syncthreads();
#pragma unroll
    for (int i = 0; i < 2; i++) {
        floatx4 li = *(const floatx4*)&lrun[wm * 32 + i * 16 + quad * 4];
#pragma unroll
        for (int j = 0; j < 4; j++) {
#pragma unroll
            for (int rg = 0; rg < 4; rg++) {
                int gr = q0 + wm * 32 + i * 16 + quad * 4 + rg;
                int gc = (int)hcol + wn * 64 + j * 16 + cl;
                O[(rowbase + gr) * HH + gc] = (bf16)(acc[i][j][rg] * li[rg]);
            }
        }
    }
}

extern "C" void kernel_launch(void* const* d_in, const int* in_sizes, int n_in,
                              void* d_out, int out_size, void* d_ws, size_t ws_size,
                              hipStream_t stream) {
    const float* x     = (const float*)d_in[0];
    const float* gamma = (const float*)d_in[1];
    const float* beta  = (const float*)d_in[2];
    const float* Wq    = (const float*)d_in[3];
    const float* Wk    = (const float*)d_in[4];
    const float* Wv    = (const float*)d_in[5];
    const float* Wo    = (const float*)d_in[6];
    float* out = (float*)d_out;

    const size_t NELEM = (size_t)MROWS * HH;  // 8.39M elements
    // ws layout (~33.6 MB): Q bf16 + V bf16 + stats f32.
    // K (bf16, 16.8 MB) parked at start of d_out (f32, 33.5 MB) — dead before
    // the final GEMM writes d_out. Attention output aliases Q (single-owner).
    bf16*  Qb    = (bf16*)d_ws;
    bf16*  Vb    = Qb + NELEM;
    float* stats = (float*)(Vb + NELEM);
    bf16*  Kb    = (bf16*)d_out;

    lnstat_k<<<MROWS, 256, 0, stream>>>(x, stats);
    dim3 gg(MROWS / 64, HH / 64);
    gemm_ln_f32_k<<<gg, 256, 0, stream>>>(x, stats, gamma, beta, Wq, Qb, HH, HH);
    gemm_ln_f32_k<<<gg, 256, 0, stream>>>(x, stats, gamma, beta, Wk, Kb, HH, HH);
    gemm_ln_f32_k<<<gg, 256, 0, stream>>>(x, stats, gamma, beta, Wv, Vb, HH, HH);
    attn_k<<<dim3(TT / 64, NHEADS, BB), 256, 0, stream>>>(Qb, Kb, Vb, Qb);
    gemm_mixed_k<<<gg, 256, 0, stream>>>(Qb, Wo, x, out, HH, HH);
}

// Round 4
// 659.405 us; speedup vs baseline: 1.1631x; 1.1631x over previous
//
#include <hip/hip_runtime.h>
#include <hip/hip_bf16.h>

#define HH 1024
#define NHEADS 8
#define HDIM 128
#define BB 4
#define TT 2048
#define MROWS (BB*TT)   // 8192

typedef __bf16 bf16;
typedef __bf16 bf16x8 __attribute__((ext_vector_type(8)));
typedef float floatx4 __attribute__((ext_vector_type(4)));

// ---------------- LayerNorm stats: one block per row, writes (mu, rs) ----------------
__global__ __launch_bounds__(256) void lnstat_k(const float* __restrict__ x,
                                                float* __restrict__ stats) {
    int row = blockIdx.x;
    const float4* xr = (const float4*)(x + (size_t)row * HH);
    int t = threadIdx.x;
    float4 v = xr[t];
    float s  = v.x + v.y + v.z + v.w;
    float s2 = v.x * v.x + v.y * v.y + v.z * v.z + v.w * v.w;
#pragma unroll
    for (int off = 32; off > 0; off >>= 1) {
        s  += __shfl_down(s,  off);
        s2 += __shfl_down(s2, off);
    }
    __shared__ float red[8];
    if ((t & 63) == 0) { red[t >> 6] = s; red[(t >> 6) + 4] = s2; }
    __syncthreads();
    if (t == 0) {
        s  = red[0] + red[1] + red[2] + red[3];
        s2 = red[4] + red[5] + red[6] + red[7];
        float mu  = s * (1.f / HH);
        float var = s2 * (1.f / HH) - mu * mu;
        stats[row * 2]     = mu;
        stats[row * 2 + 1] = rsqrtf(var + 1e-5f);
    }
}

// ---------------- GEMM, fused LN on A: C(bf16) = LN(x_f32) * W_f32^T ----------------
// tv=0: C row-major [token][channel].  tv=1: write transposed V^T layout [b][h][d][T].
__global__ __launch_bounds__(256) void gemm_ln_f32_k(const float* __restrict__ A,
                                                     const float* __restrict__ stats,
                                                     const float* __restrict__ g,
                                                     const float* __restrict__ be,
                                                     const float* __restrict__ W,
                                                     bf16* __restrict__ C,
                                                     int K, int N, int tv) {
    __shared__ __align__(16) bf16 As[64][40];
    __shared__ __align__(16) bf16 Ws[64][40];
    int m0 = blockIdx.x * 64, n0 = blockIdx.y * 64;
    int t = threadIdx.x, lane = t & 63, w = t >> 6;
    int wm = w >> 1, wn = w & 1;
    int sr = t >> 2, sc = (t & 3) * 8;
    int mrow = wm * 32 + (lane & 15), nrow = wn * 32 + (lane & 15);
    int kq = (lane >> 4) * 8;
    int arow = m0 + sr;
    float mu = stats[arow * 2], rs = stats[arow * 2 + 1];
    floatx4 acc[2][2] = {};
    for (int k0 = 0; k0 < K; k0 += 32) {
        __syncthreads();
        float vx[8], vg[8], vb[8], vw[8];
        *(float4*)&vx[0] = *(const float4*)&A[(size_t)arow * K + k0 + sc];
        *(float4*)&vx[4] = *(const float4*)&A[(size_t)arow * K + k0 + sc + 4];
        *(float4*)&vg[0] = *(const float4*)&g[k0 + sc];
        *(float4*)&vg[4] = *(const float4*)&g[k0 + sc + 4];
        *(float4*)&vb[0] = *(const float4*)&be[k0 + sc];
        *(float4*)&vb[4] = *(const float4*)&be[k0 + sc + 4];
        *(float4*)&vw[0] = *(const float4*)&W[(size_t)(n0 + sr) * K + k0 + sc];
        *(float4*)&vw[4] = *(const float4*)&W[(size_t)(n0 + sr) * K + k0 + sc + 4];
        bf16x8 nv, wv;
#pragma unroll
        for (int z = 0; z < 8; z++) {
            nv[z] = (bf16)((vx[z] - mu) * rs * vg[z] + vb[z]);
            wv[z] = (bf16)vw[z];
        }
        *(bf16x8*)&As[sr][sc] = nv;
        *(bf16x8*)&Ws[sr][sc] = wv;
        __syncthreads();
        bf16x8 a0 = *(const bf16x8*)&As[mrow][kq];
        bf16x8 a1 = *(const bf16x8*)&As[mrow + 16][kq];
        bf16x8 b0 = *(const bf16x8*)&Ws[nrow][kq];
        bf16x8 b1 = *(const bf16x8*)&Ws[nrow + 16][kq];
        acc[0][0] = __builtin_amdgcn_mfma_f32_16x16x32_bf16(a0, b0, acc[0][0], 0, 0, 0);
        acc[0][1] = __builtin_amdgcn_mfma_f32_16x16x32_bf16(a0, b1, acc[0][1], 0, 0, 0);
        acc[1][0] = __builtin_amdgcn_mfma_f32_16x16x32_bf16(a1, b0, acc[1][0], 0, 0, 0);
        acc[1][1] = __builtin_amdgcn_mfma_f32_16x16x32_bf16(a1, b1, acc[1][1], 0, 0, 0);
    }
    int quad = lane >> 4, cl = lane & 15;
#pragma unroll
    for (int i = 0; i < 2; i++)
#pragma unroll
        for (int j = 0; j < 2; j++)
#pragma unroll
            for (int rg = 0; rg < 4; rg++) {
                int gr = m0 + wm * 32 + i * 16 + quad * 4 + rg;
                int gc = n0 + wn * 32 + j * 16 + cl;
                bf16 val = (bf16)acc[i][j][rg];
                if (!tv) {
                    C[(size_t)gr * N + gc] = val;
                } else {
                    // V^T layout: [b][h][d][T];  gr = b*TT + t, gc = h*HDIM + d
                    int bb2 = gr >> 11, tt2 = gr & 2047;
                    int hh2 = gc >> 7,  dd2 = gc & 127;
                    C[((size_t)(bb2 * NHEADS + hh2) * HDIM + dd2) * TT + tt2] = val;
                }
            }
}

// ---------------- Final GEMM: out_f32 = A_bf16 * W_f32^T + R_f32 ----------------
__global__ __launch_bounds__(256) void gemm_mixed_k(const bf16* __restrict__ A,
                                                    const float* __restrict__ W,
                                                    const float* __restrict__ R,
                                                    float* __restrict__ C,
                                                    int K, int N) {
    __shared__ __align__(16) bf16 As[64][40];
    __shared__ __align__(16) bf16 Ws[64][40];
    int m0 = blockIdx.x * 64, n0 = blockIdx.y * 64;
    int t = threadIdx.x, lane = t & 63, w = t >> 6;
    int wm = w >> 1, wn = w & 1;
    int sr = t >> 2, sc = (t & 3) * 8;
    int mrow = wm * 32 + (lane & 15), nrow = wn * 32 + (lane & 15);
    int kq = (lane >> 4) * 8;
    floatx4 acc[2][2] = {};
    for (int k0 = 0; k0 < K; k0 += 32) {
        __syncthreads();
        float vw[8];
        *(float4*)&vw[0] = *(const float4*)&W[(size_t)(n0 + sr) * K + k0 + sc];
        *(float4*)&vw[4] = *(const float4*)&W[(size_t)(n0 + sr) * K + k0 + sc + 4];
        bf16x8 wv;
#pragma unroll
        for (int z = 0; z < 8; z++) wv[z] = (bf16)vw[z];
        *(bf16x8*)&As[sr][sc] = *(const bf16x8*)&A[(size_t)(m0 + sr) * K + k0 + sc];
        *(bf16x8*)&Ws[sr][sc] = wv;
        __syncthreads();
        bf16x8 a0 = *(const bf16x8*)&As[mrow][kq];
        bf16x8 a1 = *(const bf16x8*)&As[mrow + 16][kq];
        bf16x8 b0 = *(const bf16x8*)&Ws[nrow][kq];
        bf16x8 b1 = *(const bf16x8*)&Ws[nrow + 16][kq];
        acc[0][0] = __builtin_amdgcn_mfma_f32_16x16x32_bf16(a0, b0, acc[0][0], 0, 0, 0);
        acc[0][1] = __builtin_amdgcn_mfma_f32_16x16x32_bf16(a0, b1, acc[0][1], 0, 0, 0);
        acc[1][0] = __builtin_amdgcn_mfma_f32_16x16x32_bf16(a1, b0, acc[1][0], 0, 0, 0);
        acc[1][1] = __builtin_amdgcn_mfma_f32_16x16x32_bf16(a1, b1, acc[1][1], 0, 0, 0);
    }
    int quad = lane >> 4, cl = lane & 15;
#pragma unroll
    for (int i = 0; i < 2; i++)
#pragma unroll
        for (int j = 0; j < 2; j++)
#pragma unroll
            for (int rg = 0; rg < 4; rg++) {
                int gr = m0 + wm * 32 + i * 16 + quad * 4 + rg;
                int gc = n0 + wn * 32 + j * 16 + cl;
                C[(size_t)gr * N + gc] = acc[i][j][rg] + R[(size_t)gr * N + gc];
            }
}

// ---------------- Flash attention (causal), register softmax ----------------
// 64-row Q tile per block; wave w owns rows w*16..w*16+15 (full 64-col S rows).
// V comes in pre-transposed [b][h][d][T]. O may alias Q (single-owner region).
__global__ __launch_bounds__(256) void attn_k(const bf16* __restrict__ Q,
                                              const bf16* __restrict__ Kg,
                                              const bf16* __restrict__ Vt,
                                              bf16* __restrict__ O) {
    __shared__ __align__(16) bf16 Qs[64 * 136];   // 17408 B
    __shared__ __align__(16) bf16 Ks[64 * 136];   // 17408 B (Ps overlays after barrier)
    __shared__ __align__(16) bf16 Vs[128 * 72];   // 18432 B  -> total 53248 B, 3 blk/CU
    bf16* Ps = Ks;  // P[64][72] overlay; written only after all QK reads complete

    int qt = gridDim.x - 1 - blockIdx.x;  // reversed: longest blocks launch first
    int h = blockIdx.y, b = blockIdx.z;
    int t = threadIdx.x, lane = t & 63, w = t >> 6;
    int quad = lane >> 4, cl = lane & 15;
    size_t rowbase = (size_t)b * TT;
    int q0 = qt * 64;
    size_t hcol = (size_t)h * HDIM;
    size_t vtbase = (size_t)(b * NHEADS + h) * HDIM * TT;
    int myrow = w * 16 + quad * 4;  // + rg

    for (int e = t; e < 1024; e += 256) {
        int r = e >> 4, c = (e & 15) * 8;
        *(bf16x8*)&Qs[r * 136 + c] = *(const bf16x8*)&Q[(rowbase + q0 + r) * HH + hcol + c];
    }

    float m_i[4], l_i[4];
#pragma unroll
    for (int rg = 0; rg < 4; rg++) { m_i[rg] = -1e30f; l_i[rg] = 0.f; }
    floatx4 acc[8] = {};
    const float scale = 0.08838834764831845f;  // 1/sqrt(128)

    for (int kt = 0; kt <= qt; kt++) {
        __syncthreads();  // prev iter's Ps/Vs reads done (also fences Qs on kt=0... see next barrier)
        for (int e = t; e < 1024; e += 256) {
            int r = e >> 4, c = (e & 15) * 8;
            *(bf16x8*)&Ks[r * 136 + c] =
                *(const bf16x8*)&Kg[(rowbase + (size_t)kt * 64 + r) * HH + hcol + c];
        }
        for (int e = t; e < 1024; e += 256) {
            int r = e >> 3, c = (e & 7) * 8;
            *(bf16x8*)&Vs[r * 72 + c] =
                *(const bf16x8*)&Vt[vtbase + (size_t)r * TT + kt * 64 + c];
        }
        __syncthreads();
        // S rows w*16..+15 x 64 cols, 4 j-tiles
        floatx4 sacc[4] = {};
#pragma unroll
        for (int kk = 0; kk < 128; kk += 32) {
            bf16x8 aq = *(const bf16x8*)&Qs[(w * 16 + cl) * 136 + kk + quad * 8];
#pragma unroll
            for (int j = 0; j < 4; j++) {
                bf16x8 bk = *(const bf16x8*)&Ks[(j * 16 + cl) * 136 + kk + quad * 8];
                sacc[j] = __builtin_amdgcn_mfma_f32_16x16x32_bf16(aq, bk, sacc[j], 0, 0, 0);
            }
        }
        // register softmax: row = myrow+rg (held by the quad's 16 lanes), col = j*16+cl
        float p[4][4], alpha[4];
#pragma unroll
        for (int rg = 0; rg < 4; rg++) {
            float mx = -1e30f;
#pragma unroll
            for (int j = 0; j < 4; j++) {
                float sv = sacc[j][rg] * scale;
                if (kt == qt && (j * 16 + cl) > (myrow + rg)) sv = -1e30f;
                p[j][rg] = sv;
                mx = fmaxf(mx, sv);
            }
#pragma unroll
            for (int msk = 1; msk < 16; msk <<= 1) mx = fmaxf(mx, __shfl_xor(mx, msk));
            float mn = fmaxf(m_i[rg], mx);
            alpha[rg] = __expf(m_i[rg] - mn);
            m_i[rg] = mn;
            float sum = 0.f;
#pragma unroll
            for (int j = 0; j < 4; j++) {
                float pe = __expf(p[j][rg] - mn);
                p[j][rg] = pe;
                sum += pe;
            }
#pragma unroll
            for (int msk = 1; msk < 16; msk <<= 1) sum += __shfl_xor(sum, msk);
            l_i[rg] = l_i[rg] * alpha[rg] + sum;
        }
        __syncthreads();  // all waves' QK reads of Ks done before Ps overwrite
#pragma unroll
        for (int rg = 0; rg < 4; rg++)
#pragma unroll
            for (int j = 0; j < 4; j++)
                Ps[(myrow + rg) * 72 + j * 16 + cl] = (bf16)p[j][rg];
#pragma unroll
        for (int nt = 0; nt < 8; nt++)
#pragma unroll
            for (int rg = 0; rg < 4; rg++) acc[nt][rg] *= alpha[rg];
        // PV: wave reads only its OWN Ps rows -> in-wave lgkm ordering, no barrier
#pragma unroll
        for (int kti = 0; kti < 2; kti++) {
            bf16x8 pa = *(const bf16x8*)&Ps[(w * 16 + cl) * 72 + kti * 32 + quad * 8];
#pragma unroll
            for (int nt = 0; nt < 8; nt++) {
                bf16x8 vb = *(const bf16x8*)&Vs[(nt * 16 + cl) * 72 + kti * 32 + quad * 8];
                acc[nt] = __builtin_amdgcn_mfma_f32_16x16x32_bf16(pa, vb, acc[nt], 0, 0, 0);
            }
        }
    }
    float linv[4];
#pragma unroll
    for (int rg = 0; rg < 4; rg++) linv[rg] = 1.f / l_i[rg];
#pragma unroll
    for (int nt = 0; nt < 8; nt++)
#pragma unroll
        for (int rg = 0; rg < 4; rg++)
            O[(rowbase + q0 + myrow + rg) * HH + hcol + nt * 16 + cl] =
                (bf16)(acc[nt][rg] * linv[rg]);
}

extern "C" void kernel_launch(void* const* d_in, const int* in_sizes, int n_in,
                              void* d_out, int out_size, void* d_ws, size_t ws_size,
                              hipStream_t stream) {
    const float* x     = (const float*)d_in[0];
    const float* gamma = (const float*)d_in[1];
    const float* beta  = (const float*)d_in[2];
    const float* Wq    = (const float*)d_in[3];
    const float* Wk    = (const float*)d_in[4];
    const float* Wv    = (const float*)d_in[5];
    const float* Wo    = (const float*)d_in[6];
    float* out = (float*)d_out;

    const size_t NELEM = (size_t)MROWS * HH;
    // ws (~33.6 MB): Q bf16 + Vt bf16 + stats f32. K bf16 parked in d_out
    // (dead before final GEMM writes). Attention output aliases Q.
    bf16*  Qb    = (bf16*)d_ws;
    bf16*  Vb    = Qb + NELEM;   // V^T layout [b][h][d][T]
    float* stats = (float*)(Vb + NELEM);
    bf16*  Kb    = (bf16*)d_out;

    lnstat_k<<<MROWS, 256, 0, stream>>>(x, stats);
    dim3 gg(MROWS / 64, HH / 64);
    gemm_ln_f32_k<<<gg, 256, 0, stream>>>(x, stats, gamma, beta, Wq, Qb, HH, HH, 0);
    gemm_ln_f32_k<<<gg, 256, 0, stream>>>(x, stats, gamma, beta, Wk, Kb, HH, HH, 0);
    gemm_ln_f32_k<<<gg, 256, 0, stream>>>(x, stats, gamma, beta, Wv, Vb, HH, HH, 1);
    attn_k<<<dim3(TT / 64, NHEADS, BB), 256, 0, stream>>>(Qb, Kb, Vb, Qb);
    gemm_mixed_k<<<gg, 256, 0, stream>>>(Qb, Wo, x, out, HH, HH);
}

// Round 5
// 530.717 us; speedup vs baseline: 1.4451x; 1.2425x over previous
//
#include <hip/hip_runtime.h>
#include <hip/hip_bf16.h>

#define HH 1024
#define NHEADS 8
#define HDIM 128
#define BB 4
#define TT 2048
#define MROWS (BB*TT)   // 8192

typedef __bf16 bf16;
typedef __bf16 bf16x4 __attribute__((ext_vector_type(4)));
typedef __bf16 bf16x8 __attribute__((ext_vector_type(8)));
typedef float floatx4 __attribute__((ext_vector_type(4)));

// ---------------- LayerNorm stats: one block per row, writes (mu, rs) ----------------
__global__ __launch_bounds__(256) void lnstat_k(const float* __restrict__ x,
                                                float* __restrict__ stats) {
    int row = blockIdx.x;
    const float4* xr = (const float4*)(x + (size_t)row * HH);
    int t = threadIdx.x;
    float4 v = xr[t];
    float s  = v.x + v.y + v.z + v.w;
    float s2 = v.x * v.x + v.y * v.y + v.z * v.z + v.w * v.w;
#pragma unroll
    for (int off = 32; off > 0; off >>= 1) {
        s  += __shfl_down(s,  off);
        s2 += __shfl_down(s2, off);
    }
    __shared__ float red[8];
    if ((t & 63) == 0) { red[t >> 6] = s; red[(t >> 6) + 4] = s2; }
    __syncthreads();
    if (t == 0) {
        s  = red[0] + red[1] + red[2] + red[3];
        s2 = red[4] + red[5] + red[6] + red[7];
        float mu  = s * (1.f / HH);
        float var = s2 * (1.f / HH) - mu * mu;
        stats[row * 2]     = mu;
        stats[row * 2 + 1] = rsqrtf(var + 1e-5f);
    }
}

// ---------------- GEMM, fused LN on A: C(bf16) = LN(x_f32) * W_f32^T ----------------
// tv=0: C row-major [token][channel].  tv=1: write transposed V^T layout [b][h][d][T].
__global__ __launch_bounds__(256) void gemm_ln_f32_k(const float* __restrict__ A,
                                                     const float* __restrict__ stats,
                                                     const float* __restrict__ g,
                                                     const float* __restrict__ be,
                                                     const float* __restrict__ W,
                                                     bf16* __restrict__ C,
                                                     int K, int N, int tv) {
    __shared__ __align__(16) bf16 As[64][40];
    __shared__ __align__(16) bf16 Ws[64][40];
    int m0 = blockIdx.x * 64, n0 = blockIdx.y * 64;
    int t = threadIdx.x, lane = t & 63, w = t >> 6;
    int wm = w >> 1, wn = w & 1;
    int sr = t >> 2, sc = (t & 3) * 8;
    int mrow = wm * 32 + (lane & 15), nrow = wn * 32 + (lane & 15);
    int kq = (lane >> 4) * 8;
    int arow = m0 + sr;
    float mu = stats[arow * 2], rs = stats[arow * 2 + 1];
    floatx4 acc[2][2] = {};
    for (int k0 = 0; k0 < K; k0 += 32) {
        __syncthreads();
        float vx[8], vg[8], vb[8], vw[8];
        *(float4*)&vx[0] = *(const float4*)&A[(size_t)arow * K + k0 + sc];
        *(float4*)&vx[4] = *(const float4*)&A[(size_t)arow * K + k0 + sc + 4];
        *(float4*)&vg[0] = *(const float4*)&g[k0 + sc];
        *(float4*)&vg[4] = *(const float4*)&g[k0 + sc + 4];
        *(float4*)&vb[0] = *(const float4*)&be[k0 + sc];
        *(float4*)&vb[4] = *(const float4*)&be[k0 + sc + 4];
        *(float4*)&vw[0] = *(const float4*)&W[(size_t)(n0 + sr) * K + k0 + sc];
        *(float4*)&vw[4] = *(const float4*)&W[(size_t)(n0 + sr) * K + k0 + sc + 4];
        bf16x8 nv, wv;
#pragma unroll
        for (int z = 0; z < 8; z++) {
            nv[z] = (bf16)((vx[z] - mu) * rs * vg[z] + vb[z]);
            wv[z] = (bf16)vw[z];
        }
        *(bf16x8*)&As[sr][sc] = nv;
        *(bf16x8*)&Ws[sr][sc] = wv;
        __syncthreads();
        bf16x8 a0 = *(const bf16x8*)&As[mrow][kq];
        bf16x8 a1 = *(const bf16x8*)&As[mrow + 16][kq];
        bf16x8 b0 = *(const bf16x8*)&Ws[nrow][kq];
        bf16x8 b1 = *(const bf16x8*)&Ws[nrow + 16][kq];
        acc[0][0] = __builtin_amdgcn_mfma_f32_16x16x32_bf16(a0, b0, acc[0][0], 0, 0, 0);
        acc[0][1] = __builtin_amdgcn_mfma_f32_16x16x32_bf16(a0, b1, acc[0][1], 0, 0, 0);
        acc[1][0] = __builtin_amdgcn_mfma_f32_16x16x32_bf16(a1, b0, acc[1][0], 0, 0, 0);
        acc[1][1] = __builtin_amdgcn_mfma_f32_16x16x32_bf16(a1, b1, acc[1][1], 0, 0, 0);
    }
    int quad = lane >> 4, cl = lane & 15;
#pragma unroll
    for (int i = 0; i < 2; i++)
#pragma unroll
        for (int j = 0; j < 2; j++)
#pragma unroll
            for (int rg = 0; rg < 4; rg++) {
                int gr = m0 + wm * 32 + i * 16 + quad * 4 + rg;
                int gc = n0 + wn * 32 + j * 16 + cl;
                bf16 val = (bf16)acc[i][j][rg];
                if (!tv) {
                    C[(size_t)gr * N + gc] = val;
                } else {
                    int bb2 = gr >> 11, tt2 = gr & 2047;
                    int hh2 = gc >> 7,  dd2 = gc & 127;
                    C[((size_t)(bb2 * NHEADS + hh2) * HDIM + dd2) * TT + tt2] = val;
                }
            }
}

// ---------------- Final GEMM: out_f32 = A_bf16 * W_f32^T + R_f32 ----------------
__global__ __launch_bounds__(256) void gemm_mixed_k(const bf16* __restrict__ A,
                                                    const float* __restrict__ W,
                                                    const float* __restrict__ R,
                                                    float* __restrict__ C,
                                                    int K, int N) {
    __shared__ __align__(16) bf16 As[64][40];
    __shared__ __align__(16) bf16 Ws[64][40];
    int m0 = blockIdx.x * 64, n0 = blockIdx.y * 64;
    int t = threadIdx.x, lane = t & 63, w = t >> 6;
    int wm = w >> 1, wn = w & 1;
    int sr = t >> 2, sc = (t & 3) * 8;
    int mrow = wm * 32 + (lane & 15), nrow = wn * 32 + (lane & 15);
    int kq = (lane >> 4) * 8;
    floatx4 acc[2][2] = {};
    for (int k0 = 0; k0 < K; k0 += 32) {
        __syncthreads();
        float vw[8];
        *(float4*)&vw[0] = *(const float4*)&W[(size_t)(n0 + sr) * K + k0 + sc];
        *(float4*)&vw[4] = *(const float4*)&W[(size_t)(n0 + sr) * K + k0 + sc + 4];
        bf16x8 wv;
#pragma unroll
        for (int z = 0; z < 8; z++) wv[z] = (bf16)vw[z];
        *(bf16x8*)&As[sr][sc] = *(const bf16x8*)&A[(size_t)(m0 + sr) * K + k0 + sc];
        *(bf16x8*)&Ws[sr][sc] = wv;
        __syncthreads();
        bf16x8 a0 = *(const bf16x8*)&As[mrow][kq];
        bf16x8 a1 = *(const bf16x8*)&As[mrow + 16][kq];
        bf16x8 b0 = *(const bf16x8*)&Ws[nrow][kq];
        bf16x8 b1 = *(const bf16x8*)&Ws[nrow + 16][kq];
        acc[0][0] = __builtin_amdgcn_mfma_f32_16x16x32_bf16(a0, b0, acc[0][0], 0, 0, 0);
        acc[0][1] = __builtin_amdgcn_mfma_f32_16x16x32_bf16(a0, b1, acc[0][1], 0, 0, 0);
        acc[1][0] = __builtin_amdgcn_mfma_f32_16x16x32_bf16(a1, b0, acc[1][0], 0, 0, 0);
        acc[1][1] = __builtin_amdgcn_mfma_f32_16x16x32_bf16(a1, b1, acc[1][1], 0, 0, 0);
    }
    int quad = lane >> 4, cl = lane & 15;
#pragma unroll
    for (int i = 0; i < 2; i++)
#pragma unroll
        for (int j = 0; j < 2; j++)
#pragma unroll
            for (int rg = 0; rg < 4; rg++) {
                int gr = m0 + wm * 32 + i * 16 + quad * 4 + rg;
                int gc = n0 + wn * 32 + j * 16 + cl;
                C[(size_t)gr * N + gc] = acc[i][j][rg] + R[(size_t)gr * N + gc];
            }
}

// ---------------- Flash attention (causal), S^T + register P-transpose ----------------
// Wave w owns q-rows w*16..w*16+15; lane's qrow = w*16 + (lane&15), same across quads.
// S^T = K·Q^T so softmax reduces across quads only (2 shfl_xor). P goes C-layout ->
// B-operand via 16 b32 shuffles (no LDS, no barrier). K/V global loads are
// register-prefetched one kt ahead. V arrives pre-transposed [b][h][d][T].
// O aliases Q safely (single-owner region, read staged before loop).
__global__ __launch_bounds__(256) void attn_k(const bf16* __restrict__ Q,
                                              const bf16* __restrict__ Kg,
                                              const bf16* __restrict__ Vt,
                                              bf16* __restrict__ O) {
    __shared__ __align__(16) bf16 Qs[64 * 136];   // 17408 B
    __shared__ __align__(16) bf16 Ks[64 * 136];   // 17408 B
    __shared__ __align__(16) bf16 Vs[128 * 72];   // 18432 B -> 53248 B, 3 blk/CU

    int qt = gridDim.x - 1 - blockIdx.x;  // longest blocks first
    int h = blockIdx.y, b = blockIdx.z;
    int t = threadIdx.x, lane = t & 63, w = t >> 6;
    int quad = lane >> 4, cl = lane & 15;
    size_t rowbase = (size_t)b * TT;
    int q0 = qt * 64;
    size_t hcol = (size_t)h * HDIM;
    size_t vtbase = (size_t)(b * NHEADS + h) * HDIM * TT;
    int qrow = w * 16 + cl;

    for (int e = t; e < 1024; e += 256) {
        int r = e >> 4, c = (e & 15) * 8;
        *(bf16x8*)&Qs[r * 136 + c] = *(const bf16x8*)&Q[(rowbase + q0 + r) * HH + hcol + c];
    }

    float m_i = -1e30f, l_i = 0.f;
    floatx4 acc[8] = {};   // O^T: acc[nt][rg] = O[qrow][d = nt*16 + quad*4 + rg]
    const float scale = 0.08838834764831845f;  // 1/sqrt(128)

    bf16x8 kr[4], vr[4];
    auto fetch = [&](int ktf) {
#pragma unroll
        for (int i = 0; i < 4; i++) {
            int e = t + i * 256;
            kr[i] = *(const bf16x8*)&Kg[(rowbase + (size_t)ktf * 64 + (e >> 4)) * HH + hcol + (e & 15) * 8];
            vr[i] = *(const bf16x8*)&Vt[vtbase + (size_t)(e >> 3) * TT + ktf * 64 + (e & 7) * 8];
        }
    };
    fetch(0);

    for (int kt = 0; kt <= qt; kt++) {
        __syncthreads();  // prev iter's Ks/Vs reads complete
#pragma unroll
        for (int i = 0; i < 4; i++) {
            int e = t + i * 256;
            *(bf16x8*)&Ks[(e >> 4) * 136 + (e & 15) * 8] = kr[i];
            *(bf16x8*)&Vs[(e >> 3) * 72 + (e & 7) * 8]   = vr[i];
        }
        if (kt < qt) fetch(kt + 1);  // in flight across the whole compute body
        __syncthreads();

        // S^T: C[kcol = jj*16 + quad*4 + rg][qrow = cl]   (A=K-frag, B=Q-frag)
        floatx4 sacc[4] = {};
#pragma unroll
        for (int kk = 0; kk < 128; kk += 32) {
            bf16x8 bq = *(const bf16x8*)&Qs[qrow * 136 + kk + quad * 8];
#pragma unroll
            for (int jj = 0; jj < 4; jj++) {
                bf16x8 ak = *(const bf16x8*)&Ks[(jj * 16 + cl) * 136 + kk + quad * 8];
                sacc[jj] = __builtin_amdgcn_mfma_f32_16x16x32_bf16(ak, bq, sacc[jj], 0, 0, 0);
            }
        }
        // softmax: lane holds 16 kcols of row qrow; reduce across quads
        float p[4][4];
        float mx = -1e30f;
#pragma unroll
        for (int jj = 0; jj < 4; jj++)
#pragma unroll
            for (int rg = 0; rg < 4; rg++) {
                float sv = sacc[jj][rg] * scale;
                if (kt == qt && (jj * 16 + quad * 4 + rg) > qrow) sv = -1e30f;
                p[jj][rg] = sv;
                mx = fmaxf(mx, sv);
            }
        mx = fmaxf(mx, __shfl_xor(mx, 16));
        mx = fmaxf(mx, __shfl_xor(mx, 32));
        float mn = fmaxf(m_i, mx);
        float alpha = __expf(m_i - mn);
        m_i = mn;
        float sum = 0.f;
#pragma unroll
        for (int jj = 0; jj < 4; jj++)
#pragma unroll
            for (int rg = 0; rg < 4; rg++) {
                float pe = __expf(p[jj][rg] - mn);
                p[jj][rg] = pe;
                sum += pe;
            }
        sum += __shfl_xor(sum, 16);
        sum += __shfl_xor(sum, 32);
        l_i = l_i * alpha + sum;

        // pack p[jj][0..3] -> bf16x4 as 2 ints for shuffling
        int pk[4][2];
#pragma unroll
        for (int jj = 0; jj < 4; jj++) {
            union { bf16x4 v; int i2[2]; } u;
#pragma unroll
            for (int rg = 0; rg < 4; rg++) u.v[rg] = (bf16)p[jj][rg];
            pk[jj][0] = u.i2[0];
            pk[jj][1] = u.i2[1];
        }
#pragma unroll
        for (int nt = 0; nt < 8; nt++) acc[nt] *= alpha;

        // PV per kti: rebuild P B-operand frag via cross-quad shuffles (fixed cl)
        int La = ((2 * quad) & 3) * 16 + cl;
        int Lb = ((2 * quad + 1) & 3) * 16 + cl;
        bool hi = (quad >> 1) & 1;
#pragma unroll
        for (int kti = 0; kti < 2; kti++) {
            int j0 = kti * 2, j1 = kti * 2 + 1;
            int a0x = __shfl(pk[j0][0], La), a0y = __shfl(pk[j0][1], La);
            int a1x = __shfl(pk[j1][0], La), a1y = __shfl(pk[j1][1], La);
            int b0x = __shfl(pk[j0][0], Lb), b0y = __shfl(pk[j0][1], Lb);
            int b1x = __shfl(pk[j1][0], Lb), b1y = __shfl(pk[j1][1], Lb);
            union { bf16x8 v; int i4[4]; } pu;
            pu.i4[0] = hi ? a1x : a0x;
            pu.i4[1] = hi ? a1y : a0y;
            pu.i4[2] = hi ? b1x : b0x;
            pu.i4[3] = hi ? b1y : b0y;
#pragma unroll
            for (int nt = 0; nt < 8; nt++) {
                bf16x8 av = *(const bf16x8*)&Vs[(nt * 16 + cl) * 72 + kti * 32 + quad * 8];
                acc[nt] = __builtin_amdgcn_mfma_f32_16x16x32_bf16(av, pu.v, acc[nt], 0, 0, 0);
            }
        }
    }

    float linv = 1.f / l_i;
#pragma unroll
    for (int nt = 0; nt < 8; nt++) {
        bf16x4 o4;
#pragma unroll
        for (int rg = 0; rg < 4; rg++) o4[rg] = (bf16)(acc[nt][rg] * linv);
        *(bf16x4*)&O[(rowbase + q0 + qrow) * HH + hcol + nt * 16 + quad * 4] = o4;
    }
}

extern "C" void kernel_launch(void* const* d_in, const int* in_sizes, int n_in,
                              void* d_out, int out_size, void* d_ws, size_t ws_size,
                              hipStream_t stream) {
    const float* x     = (const float*)d_in[0];
    const float* gamma = (const float*)d_in[1];
    const float* beta  = (const float*)d_in[2];
    const float* Wq    = (const float*)d_in[3];
    const float* Wk    = (const float*)d_in[4];
    const float* Wv    = (const float*)d_in[5];
    const float* Wo    = (const float*)d_in[6];
    float* out = (float*)d_out;

    const size_t NELEM = (size_t)MROWS * HH;
    bf16*  Qb    = (bf16*)d_ws;
    bf16*  Vb    = Qb + NELEM;   // V^T layout [b][h][d][T]
    float* stats = (float*)(Vb + NELEM);
    bf16*  Kb    = (bf16*)d_out; // parked in d_out, dead before final GEMM writes

    lnstat_k<<<MROWS, 256, 0, stream>>>(x, stats);
    dim3 gg(MROWS / 64, HH / 64);
    gemm_ln_f32_k<<<gg, 256, 0, stream>>>(x, stats, gamma, beta, Wq, Qb, HH, HH, 0);
    gemm_ln_f32_k<<<gg, 256, 0, stream>>>(x, stats, gamma, beta, Wk, Kb, HH, HH, 0);
    gemm_ln_f32_k<<<gg, 256, 0, stream>>>(x, stats, gamma, beta, Wv, Vb, HH, HH, 1);
    attn_k<<<dim3(TT / 64, NHEADS, BB), 256, 0, stream>>>(Qb, Kb, Vb, Qb);
    gemm_mixed_k<<<gg, 256, 0, stream>>>(Qb, Wo, x, out, HH, HH);
}

// Round 6
// 384.714 us; speedup vs baseline: 1.9936x; 1.3795x over previous
//
#include <hip/hip_runtime.h>
#include <hip/hip_bf16.h>

#define HH 1024
#define NHEADS 8
#define HDIM 128
#define BB 4
#define TT 2048
#define MROWS (BB*TT)   // 8192

typedef __bf16 bf16;
typedef __bf16 bf16x4 __attribute__((ext_vector_type(4)));
typedef __bf16 bf16x8 __attribute__((ext_vector_type(8)));
typedef float floatx4 __attribute__((ext_vector_type(4)));

// ---------------- LayerNorm stats: one block per row, writes (mu, rs) ----------------
__global__ __launch_bounds__(256) void lnstat_k(const float* __restrict__ x,
                                                float* __restrict__ stats) {
    int row = blockIdx.x;
    const float4* xr = (const float4*)(x + (size_t)row * HH);
    int t = threadIdx.x;
    float4 v = xr[t];
    float s  = v.x + v.y + v.z + v.w;
    float s2 = v.x * v.x + v.y * v.y + v.z * v.z + v.w * v.w;
#pragma unroll
    for (int off = 32; off > 0; off >>= 1) {
        s  += __shfl_down(s,  off);
        s2 += __shfl_down(s2, off);
    }
    __shared__ float red[8];
    if ((t & 63) == 0) { red[t >> 6] = s; red[(t >> 6) + 4] = s2; }
    __syncthreads();
    if (t == 0) {
        s  = red[0] + red[1] + red[2] + red[3];
        s2 = red[4] + red[5] + red[6] + red[7];
        float mu  = s * (1.f / HH);
        float var = s2 * (1.f / HH) - mu * mu;
        stats[row * 2]     = mu;
        stats[row * 2 + 1] = rsqrtf(var + 1e-5f);
    }
}

// ------------- 128x128 GEMM, fused LN on A: C(bf16) = LN(x_f32) * W_f32^T -------------
// BK=32, 4 waves in 2x2, each wave 64x64 via 4x4 of 16x16x32 MFMA.
// Next K-slab register-prefetched during MFMA body. tv=1: V^T layout [b][h][d][T].
__global__ __launch_bounds__(256) void gemm_ln128_k(const float* __restrict__ A,
                                                    const float* __restrict__ stats,
                                                    const float* __restrict__ g,
                                                    const float* __restrict__ be,
                                                    const float* __restrict__ W,
                                                    bf16* __restrict__ C, int tv) {
    const int K = HH, N = HH;
    __shared__ __align__(16) bf16 As[128][40];  // +8 pad -> 2-way alias (free)
    __shared__ __align__(16) bf16 Ws[128][40];
    int m0 = blockIdx.x * 128, n0 = blockIdx.y * 128;
    int t = threadIdx.x, lane = t & 63, w = t >> 6;
    int wm = w >> 1, wn = w & 1;
    int quad = lane >> 4, cl = lane & 15, kq = quad * 8;
    int r0 = t >> 3, c0 = (t & 7) * 4;   // r0 in [0,32), +i*32; c0 i-invariant
    float mu[4], rs[4];
#pragma unroll
    for (int i = 0; i < 4; i++) {
        int r = m0 + r0 + i * 32;
        mu[i] = stats[r * 2]; rs[i] = stats[r * 2 + 1];
    }
    float4 va[4], vw[4], vg, vb;
    auto fetch = [&](int k0) {
        vg = *(const float4*)&g[k0 + c0];
        vb = *(const float4*)&be[k0 + c0];
#pragma unroll
        for (int i = 0; i < 4; i++) {
            va[i] = *(const float4*)&A[(size_t)(m0 + r0 + i * 32) * K + k0 + c0];
            vw[i] = *(const float4*)&W[(size_t)(n0 + r0 + i * 32) * K + k0 + c0];
        }
    };
    fetch(0);
    floatx4 acc[4][4] = {};
    for (int k0 = 0; k0 < K; k0 += 32) {
        __syncthreads();
#pragma unroll
        for (int i = 0; i < 4; i++) {
            const float* pa = (const float*)&va[i];
            const float* pw = (const float*)&vw[i];
            const float* pg = (const float*)&vg;
            const float* pb = (const float*)&vb;
            bf16x4 nv, wv;
#pragma unroll
            for (int z = 0; z < 4; z++) {
                nv[z] = (bf16)((pa[z] - mu[i]) * rs[i] * pg[z] + pb[z]);
                wv[z] = (bf16)pw[z];
            }
            *(bf16x4*)&As[r0 + i * 32][c0] = nv;
            *(bf16x4*)&Ws[r0 + i * 32][c0] = wv;
        }
        if (k0 + 32 < K) fetch(k0 + 32);  // in flight during MFMA body
        __syncthreads();
        bf16x8 af[4], bfr[4];
#pragma unroll
        for (int i = 0; i < 4; i++) af[i]  = *(const bf16x8*)&As[wm * 64 + i * 16 + cl][kq];
#pragma unroll
        for (int j = 0; j < 4; j++) bfr[j] = *(const bf16x8*)&Ws[wn * 64 + j * 16 + cl][kq];
#pragma unroll
        for (int i = 0; i < 4; i++)
#pragma unroll
            for (int j = 0; j < 4; j++)
                acc[i][j] = __builtin_amdgcn_mfma_f32_16x16x32_bf16(af[i], bfr[j], acc[i][j], 0, 0, 0);
    }
    // C/D layout: col = lane&15, row = quad*4 + reg
#pragma unroll
    for (int i = 0; i < 4; i++)
#pragma unroll
        for (int j = 0; j < 4; j++)
#pragma unroll
            for (int rg = 0; rg < 4; rg++) {
                int gr = m0 + wm * 64 + i * 16 + quad * 4 + rg;
                int gc = n0 + wn * 64 + j * 16 + cl;
                bf16 val = (bf16)acc[i][j][rg];
                if (!tv) {
                    C[(size_t)gr * N + gc] = val;
                } else {
                    int bb2 = gr >> 11, tt2 = gr & 2047;
                    int hh2 = gc >> 7,  dd2 = gc & 127;
                    C[((size_t)(bb2 * NHEADS + hh2) * HDIM + dd2) * TT + tt2] = val;
                }
            }
}

// ------------- 128x128 final GEMM: out_f32 = A_bf16 * W_f32^T + R_f32 -------------
__global__ __launch_bounds__(256) void gemm_fin128_k(const bf16* __restrict__ A,
                                                     const float* __restrict__ W,
                                                     const float* __restrict__ R,
                                                     float* __restrict__ C) {
    const int K = HH, N = HH;
    __shared__ __align__(16) bf16 As[128][40];
    __shared__ __align__(16) bf16 Ws[128][40];
    int m0 = blockIdx.x * 128, n0 = blockIdx.y * 128;
    int t = threadIdx.x, lane = t & 63, w = t >> 6;
    int wm = w >> 1, wn = w & 1;
    int quad = lane >> 4, cl = lane & 15, kq = quad * 8;
    int ra = t >> 2, ca = (t & 3) * 8;   // A: bf16, 4 lanes/row
    int r0 = t >> 3, c0 = (t & 7) * 4;   // W: f32, 8 lanes/row
    bf16x8 va8[2];
    float4 vw[4];
    auto fetch = [&](int k0) {
#pragma unroll
        for (int i = 0; i < 2; i++)
            va8[i] = *(const bf16x8*)&A[(size_t)(m0 + ra + i * 64) * K + k0 + ca];
#pragma unroll
        for (int i = 0; i < 4; i++)
            vw[i] = *(const float4*)&W[(size_t)(n0 + r0 + i * 32) * K + k0 + c0];
    };
    fetch(0);
    floatx4 acc[4][4] = {};
    for (int k0 = 0; k0 < K; k0 += 32) {
        __syncthreads();
#pragma unroll
        for (int i = 0; i < 2; i++)
            *(bf16x8*)&As[ra + i * 64][ca] = va8[i];
#pragma unroll
        for (int i = 0; i < 4; i++) {
            const float* pw = (const float*)&vw[i];
            bf16x4 wv;
#pragma unroll
            for (int z = 0; z < 4; z++) wv[z] = (bf16)pw[z];
            *(bf16x4*)&Ws[r0 + i * 32][c0] = wv;
        }
        if (k0 + 32 < K) fetch(k0 + 32);
        __syncthreads();
        bf16x8 af[4], bfr[4];
#pragma unroll
        for (int i = 0; i < 4; i++) af[i]  = *(const bf16x8*)&As[wm * 64 + i * 16 + cl][kq];
#pragma unroll
        for (int j = 0; j < 4; j++) bfr[j] = *(const bf16x8*)&Ws[wn * 64 + j * 16 + cl][kq];
#pragma unroll
        for (int i = 0; i < 4; i++)
#pragma unroll
            for (int j = 0; j < 4; j++)
                acc[i][j] = __builtin_amdgcn_mfma_f32_16x16x32_bf16(af[i], bfr[j], acc[i][j], 0, 0, 0);
    }
#pragma unroll
    for (int i = 0; i < 4; i++)
#pragma unroll
        for (int j = 0; j < 4; j++)
#pragma unroll
            for (int rg = 0; rg < 4; rg++) {
                int gr = m0 + wm * 64 + i * 16 + quad * 4 + rg;
                int gc = n0 + wn * 64 + j * 16 + cl;
                C[(size_t)gr * N + gc] = acc[i][j][rg] + R[(size_t)gr * N + gc];
            }
}

// ---------------- Flash attention (causal), S^T + register P-transpose ----------------
// (unchanged from round 5 — 158 µs, next target after GEMMs)
__global__ __launch_bounds__(256) void attn_k(const bf16* __restrict__ Q,
                                              const bf16* __restrict__ Kg,
                                              const bf16* __restrict__ Vt,
                                              bf16* __restrict__ O) {
    __shared__ __align__(16) bf16 Qs[64 * 136];
    __shared__ __align__(16) bf16 Ks[64 * 136];
    __shared__ __align__(16) bf16 Vs[128 * 72];

    int qt = gridDim.x - 1 - blockIdx.x;
    int h = blockIdx.y, b = blockIdx.z;
    int t = threadIdx.x, lane = t & 63, w = t >> 6;
    int quad = lane >> 4, cl = lane & 15;
    size_t rowbase = (size_t)b * TT;
    int q0 = qt * 64;
    size_t hcol = (size_t)h * HDIM;
    size_t vtbase = (size_t)(b * NHEADS + h) * HDIM * TT;
    int qrow = w * 16 + cl;

    for (int e = t; e < 1024; e += 256) {
        int r = e >> 4, c = (e & 15) * 8;
        *(bf16x8*)&Qs[r * 136 + c] = *(const bf16x8*)&Q[(rowbase + q0 + r) * HH + hcol + c];
    }

    float m_i = -1e30f, l_i = 0.f;
    floatx4 acc[8] = {};
    const float scale = 0.08838834764831845f;

    bf16x8 kr[4], vr[4];
    auto fetch = [&](int ktf) {
#pragma unroll
        for (int i = 0; i < 4; i++) {
            int e = t + i * 256;
            kr[i] = *(const bf16x8*)&Kg[(rowbase + (size_t)ktf * 64 + (e >> 4)) * HH + hcol + (e & 15) * 8];
            vr[i] = *(const bf16x8*)&Vt[vtbase + (size_t)(e >> 3) * TT + ktf * 64 + (e & 7) * 8];
        }
    };
    fetch(0);

    for (int kt = 0; kt <= qt; kt++) {
        __syncthreads();
#pragma unroll
        for (int i = 0; i < 4; i++) {
            int e = t + i * 256;
            *(bf16x8*)&Ks[(e >> 4) * 136 + (e & 15) * 8] = kr[i];
            *(bf16x8*)&Vs[(e >> 3) * 72 + (e & 7) * 8]   = vr[i];
        }
        if (kt < qt) fetch(kt + 1);
        __syncthreads();

        floatx4 sacc[4] = {};
#pragma unroll
        for (int kk = 0; kk < 128; kk += 32) {
            bf16x8 bq = *(const bf16x8*)&Qs[qrow * 136 + kk + quad * 8];
#pragma unroll
            for (int jj = 0; jj < 4; jj++) {
                bf16x8 ak = *(const bf16x8*)&Ks[(jj * 16 + cl) * 136 + kk + quad * 8];
                sacc[jj] = __builtin_amdgcn_mfma_f32_16x16x32_bf16(ak, bq, sacc[jj], 0, 0, 0);
            }
        }
        float p[4][4];
        float mx = -1e30f;
#pragma unroll
        for (int jj = 0; jj < 4; jj++)
#pragma unroll
            for (int rg = 0; rg < 4; rg++) {
                float sv = sacc[jj][rg] * scale;
                if (kt == qt && (jj * 16 + quad * 4 + rg) > qrow) sv = -1e30f;
                p[jj][rg] = sv;
                mx = fmaxf(mx, sv);
            }
        mx = fmaxf(mx, __shfl_xor(mx, 16));
        mx = fmaxf(mx, __shfl_xor(mx, 32));
        float mn = fmaxf(m_i, mx);
        float alpha = __expf(m_i - mn);
        m_i = mn;
        float sum = 0.f;
#pragma unroll
        for (int jj = 0; jj < 4; jj++)
#pragma unroll
            for (int rg = 0; rg < 4; rg++) {
                float pe = __expf(p[jj][rg] - mn);
                p[jj][rg] = pe;
                sum += pe;
            }
        sum += __shfl_xor(sum, 16);
        sum += __shfl_xor(sum, 32);
        l_i = l_i * alpha + sum;

        int pk[4][2];
#pragma unroll
        for (int jj = 0; jj < 4; jj++) {
            union { bf16x4 v; int i2[2]; } u;
#pragma unroll
            for (int rg = 0; rg < 4; rg++) u.v[rg] = (bf16)p[jj][rg];
            pk[jj][0] = u.i2[0];
            pk[jj][1] = u.i2[1];
        }
#pragma unroll
        for (int nt = 0; nt < 8; nt++) acc[nt] *= alpha;

        int La = ((2 * quad) & 3) * 16 + cl;
        int Lb = ((2 * quad + 1) & 3) * 16 + cl;
        bool hi = (quad >> 1) & 1;
#pragma unroll
        for (int kti = 0; kti < 2; kti++) {
            int j0 = kti * 2, j1 = kti * 2 + 1;
            int a0x = __shfl(pk[j0][0], La), a0y = __shfl(pk[j0][1], La);
            int a1x = __shfl(pk[j1][0], La), a1y = __shfl(pk[j1][1], La);
            int b0x = __shfl(pk[j0][0], Lb), b0y = __shfl(pk[j0][1], Lb);
            int b1x = __shfl(pk[j1][0], Lb), b1y = __shfl(pk[j1][1], Lb);
            union { bf16x8 v; int i4[4]; } pu;
            pu.i4[0] = hi ? a1x : a0x;
            pu.i4[1] = hi ? a1y : a0y;
            pu.i4[2] = hi ? b1x : b0x;
            pu.i4[3] = hi ? b1y : b0y;
#pragma unroll
            for (int nt = 0; nt < 8; nt++) {
                bf16x8 av = *(const bf16x8*)&Vs[(nt * 16 + cl) * 72 + kti * 32 + quad * 8];
                acc[nt] = __builtin_amdgcn_mfma_f32_16x16x32_bf16(av, pu.v, acc[nt], 0, 0, 0);
            }
        }
    }

    float linv = 1.f / l_i;
#pragma unroll
    for (int nt = 0; nt < 8; nt++) {
        bf16x4 o4;
#pragma unroll
        for (int rg = 0; rg < 4; rg++) o4[rg] = (bf16)(acc[nt][rg] * linv);
        *(bf16x4*)&O[(rowbase + q0 + qrow) * HH + hcol + nt * 16 + quad * 4] = o4;
    }
}

extern "C" void kernel_launch(void* const* d_in, const int* in_sizes, int n_in,
                              void* d_out, int out_size, void* d_ws, size_t ws_size,
                              hipStream_t stream) {
    const float* x     = (const float*)d_in[0];
    const float* gamma = (const float*)d_in[1];
    const float* beta  = (const float*)d_in[2];
    const float* Wq    = (const float*)d_in[3];
    const float* Wk    = (const float*)d_in[4];
    const float* Wv    = (const float*)d_in[5];
    const float* Wo    = (const float*)d_in[6];
    float* out = (float*)d_out;

    const size_t NELEM = (size_t)MROWS * HH;
    bf16*  Qb    = (bf16*)d_ws;
    bf16*  Vb    = Qb + NELEM;   // V^T layout [b][h][d][T]
    float* stats = (float*)(Vb + NELEM);
    bf16*  Kb    = (bf16*)d_out; // parked in d_out, dead before final GEMM writes

    lnstat_k<<<MROWS, 256, 0, stream>>>(x, stats);
    dim3 gg(MROWS / 128, HH / 128);
    gemm_ln128_k<<<gg, 256, 0, stream>>>(x, stats, gamma, beta, Wq, Qb, 0);
    gemm_ln128_k<<<gg, 256, 0, stream>>>(x, stats, gamma, beta, Wk, Kb, 0);
    gemm_ln128_k<<<gg, 256, 0, stream>>>(x, stats, gamma, beta, Wv, Vb, 1);
    attn_k<<<dim3(TT / 64, NHEADS, BB), 256, 0, stream>>>(Qb, Kb, Vb, Qb);
    gemm_fin128_k<<<gg, 256, 0, stream>>>(Qb, Wo, x, out);
}

// Round 7
// 342.340 us; speedup vs baseline: 2.2403x; 1.1238x over previous
//
#include <hip/hip_runtime.h>
#include <hip/hip_bf16.h>

#define HH 1024
#define NHEADS 8
#define HDIM 128
#define BB 4
#define TT 2048
#define MROWS (BB*TT)   // 8192

typedef __bf16 bf16;
typedef __bf16 bf16x4 __attribute__((ext_vector_type(4)));
typedef __bf16 bf16x8 __attribute__((ext_vector_type(8)));
typedef float floatx4 __attribute__((ext_vector_type(4)));

// ---------------- LayerNorm: one block per row, f32 in -> bf16 out ----------------
__global__ __launch_bounds__(256) void ln_k(const float* __restrict__ x,
                                            const float* __restrict__ g,
                                            const float* __restrict__ be,
                                            bf16* __restrict__ xn) {
    int row = blockIdx.x;
    int t = threadIdx.x;
    float4 v4 = ((const float4*)(x + (size_t)row * HH))[t];
    const float* v = (const float*)&v4;
    float s = v[0] + v[1] + v[2] + v[3];
    float s2 = v[0]*v[0] + v[1]*v[1] + v[2]*v[2] + v[3]*v[3];
#pragma unroll
    for (int off = 32; off > 0; off >>= 1) {
        s  += __shfl_down(s,  off);
        s2 += __shfl_down(s2, off);
    }
    __shared__ float red[8];
    if ((t & 63) == 0) { red[t >> 6] = s; red[(t >> 6) + 4] = s2; }
    __syncthreads();
    s  = red[0] + red[1] + red[2] + red[3];
    s2 = red[4] + red[5] + red[6] + red[7];
    float mu  = s * (1.f / HH);
    float var = s2 * (1.f / HH) - mu * mu;
    float rs  = rsqrtf(var + 1e-5f);
    float4 g4 = ((const float4*)g)[t];
    float4 b4 = ((const float4*)be)[t];
    const float* gv = (const float*)&g4;
    const float* bv = (const float*)&b4;
    bf16x4 o;
#pragma unroll
    for (int z = 0; z < 4; z++) o[z] = (bf16)((v[z] - mu) * rs * gv[z] + bv[z]);
    ((bf16x4*)(xn + (size_t)row * HH))[t] = o;
}

// ---------------- Weight convert f32 -> bf16 (1024x1024) ----------------
__global__ __launch_bounds__(256) void convw_k(const float* __restrict__ W,
                                               bf16* __restrict__ Wb) {
    int idx = blockIdx.x * 256 + threadIdx.x;
    float4 v4 = ((const float4*)W)[idx];
    const float* v = (const float*)&v4;
    bf16x4 o;
#pragma unroll
    for (int z = 0; z < 4; z++) o[z] = (bf16)v[z];
    ((bf16x4*)Wb)[idx] = o;
}

// ------------- 128x128 pure-bf16 GEMM: C(bf16) = A * W^T; tv=1 -> V^T layout -------------
__global__ __launch_bounds__(256) void gemm_bf128_k(const bf16* __restrict__ A,
                                                    const bf16* __restrict__ W,
                                                    bf16* __restrict__ C, int tv) {
    const int K = HH, N = HH;
    __shared__ __align__(16) bf16 As[128][40];
    __shared__ __align__(16) bf16 Ws[128][40];
    int m0 = blockIdx.x * 128, n0 = blockIdx.y * 128;
    int t = threadIdx.x, lane = t & 63, w = t >> 6;
    int wm = w >> 1, wn = w & 1;
    int quad = lane >> 4, cl = lane & 15, kq = quad * 8;
    int ra = t >> 2, ca = (t & 3) * 8;
    bf16x8 va[2], vw[2];
    auto fetch = [&](int k0) {
#pragma unroll
        for (int i = 0; i < 2; i++) {
            va[i] = *(const bf16x8*)&A[(size_t)(m0 + ra + i * 64) * K + k0 + ca];
            vw[i] = *(const bf16x8*)&W[(size_t)(n0 + ra + i * 64) * K + k0 + ca];
        }
    };
    fetch(0);
    floatx4 acc[4][4] = {};
    for (int k0 = 0; k0 < K; k0 += 32) {
        __syncthreads();
#pragma unroll
        for (int i = 0; i < 2; i++) {
            *(bf16x8*)&As[ra + i * 64][ca] = va[i];
            *(bf16x8*)&Ws[ra + i * 64][ca] = vw[i];
        }
        if (k0 + 32 < K) fetch(k0 + 32);
        __syncthreads();
        bf16x8 af[4], bfr[4];
#pragma unroll
        for (int i = 0; i < 4; i++) af[i]  = *(const bf16x8*)&As[wm * 64 + i * 16 + cl][kq];
#pragma unroll
        for (int j = 0; j < 4; j++) bfr[j] = *(const bf16x8*)&Ws[wn * 64 + j * 16 + cl][kq];
#pragma unroll
        for (int i = 0; i < 4; i++)
#pragma unroll
            for (int j = 0; j < 4; j++)
                acc[i][j] = __builtin_amdgcn_mfma_f32_16x16x32_bf16(af[i], bfr[j], acc[i][j], 0, 0, 0);
    }
#pragma unroll
    for (int i = 0; i < 4; i++)
#pragma unroll
        for (int j = 0; j < 4; j++)
#pragma unroll
            for (int rg = 0; rg < 4; rg++) {
                int gr = m0 + wm * 64 + i * 16 + quad * 4 + rg;
                int gc = n0 + wn * 64 + j * 16 + cl;
                bf16 val = (bf16)acc[i][j][rg];
                if (!tv) {
                    C[(size_t)gr * N + gc] = val;
                } else {
                    int bb2 = gr >> 11, tt2 = gr & 2047;
                    int hh2 = gc >> 7,  dd2 = gc & 127;
                    C[((size_t)(bb2 * NHEADS + hh2) * HDIM + dd2) * TT + tt2] = val;
                }
            }
}

// ------------- 128x128 final GEMM: out_f32 = A_bf16 * Wb_bf16^T + R_f32 -------------
__global__ __launch_bounds__(256) void gemm_finbf_k(const bf16* __restrict__ A,
                                                    const bf16* __restrict__ W,
                                                    const float* __restrict__ R,
                                                    float* __restrict__ C) {
    const int K = HH, N = HH;
    __shared__ __align__(16) bf16 As[128][40];
    __shared__ __align__(16) bf16 Ws[128][40];
    int m0 = blockIdx.x * 128, n0 = blockIdx.y * 128;
    int t = threadIdx.x, lane = t & 63, w = t >> 6;
    int wm = w >> 1, wn = w & 1;
    int quad = lane >> 4, cl = lane & 15, kq = quad * 8;
    int ra = t >> 2, ca = (t & 3) * 8;
    bf16x8 va[2], vw[2];
    auto fetch = [&](int k0) {
#pragma unroll
        for (int i = 0; i < 2; i++) {
            va[i] = *(const bf16x8*)&A[(size_t)(m0 + ra + i * 64) * K + k0 + ca];
            vw[i] = *(const bf16x8*)&W[(size_t)(n0 + ra + i * 64) * K + k0 + ca];
        }
    };
    fetch(0);
    floatx4 acc[4][4] = {};
    for (int k0 = 0; k0 < K; k0 += 32) {
        __syncthreads();
#pragma unroll
        for (int i = 0; i < 2; i++) {
            *(bf16x8*)&As[ra + i * 64][ca] = va[i];
            *(bf16x8*)&Ws[ra + i * 64][ca] = vw[i];
        }
        if (k0 + 32 < K) fetch(k0 + 32);
        __syncthreads();
        bf16x8 af[4], bfr[4];
#pragma unroll
        for (int i = 0; i < 4; i++) af[i]  = *(const bf16x8*)&As[wm * 64 + i * 16 + cl][kq];
#pragma unroll
        for (int j = 0; j < 4; j++) bfr[j] = *(const bf16x8*)&Ws[wn * 64 + j * 16 + cl][kq];
#pragma unroll
        for (int i = 0; i < 4; i++)
#pragma unroll
            for (int j = 0; j < 4; j++)
                acc[i][j] = __builtin_amdgcn_mfma_f32_16x16x32_bf16(af[i], bfr[j], acc[i][j], 0, 0, 0);
    }
#pragma unroll
    for (int i = 0; i < 4; i++)
#pragma unroll
        for (int j = 0; j < 4; j++)
#pragma unroll
            for (int rg = 0; rg < 4; rg++) {
                int gr = m0 + wm * 64 + i * 16 + quad * 4 + rg;
                int gc = n0 + wn * 64 + j * 16 + cl;
                C[(size_t)gr * N + gc] = acc[i][j][rg] + R[(size_t)gr * N + gc];
            }
}

// ---------------- Flash attention (causal): 128-row Q tile, 2 col-groups/wave ----------------
// Wave w owns q-rows w*32 .. w*32+31 (groups g=0,1: qrow = w*32+g*16+cl).
// Q fragments hoisted to registers once; K/V LDS reads serve both groups.
// V pre-transposed [b][h][d][T]. O aliases Q (single-owner region per block).
__global__ __launch_bounds__(256, 2) void attn_k(const bf16* __restrict__ Q,
                                                 const bf16* __restrict__ Kg,
                                                 const bf16* __restrict__ Vt,
                                                 bf16* __restrict__ O) {
    __shared__ __align__(16) bf16 Qs[128 * 136];  // 34816 B
    __shared__ __align__(16) bf16 Ks[64 * 136];   // 17408 B
    __shared__ __align__(16) bf16 Vs[128 * 72];   // 18432 B -> 70656 B, 2 blk/CU

    int qt = gridDim.x - 1 - blockIdx.x;  // longest blocks first
    int h = blockIdx.y, b = blockIdx.z;
    int t = threadIdx.x, lane = t & 63, w = t >> 6;
    int quad = lane >> 4, cl = lane & 15;
    size_t rowbase = (size_t)b * TT;
    int q0 = qt * 128;
    size_t hcol = (size_t)h * HDIM;
    size_t vtbase = (size_t)(b * NHEADS + h) * HDIM * TT;

    for (int e = t; e < 2048; e += 256) {
        int r = e >> 4, c = (e & 15) * 8;
        *(bf16x8*)&Qs[r * 136 + c] = *(const bf16x8*)&Q[(rowbase + q0 + r) * HH + hcol + c];
    }
    __syncthreads();
    bf16x8 qf[4][2];
#pragma unroll
    for (int kk = 0; kk < 4; kk++)
#pragma unroll
        for (int g = 0; g < 2; g++)
            qf[kk][g] = *(const bf16x8*)&Qs[(w * 32 + g * 16 + cl) * 136 + kk * 32 + quad * 8];

    float m_i[2] = {-1e30f, -1e30f}, l_i[2] = {0.f, 0.f};
    floatx4 acc[8][2] = {};
    const float scale = 0.08838834764831845f;  // 1/sqrt(128)

    bf16x8 kr[4], vr[4];
    auto fetch = [&](int ktf) {
#pragma unroll
        for (int i = 0; i < 4; i++) {
            int e = t + i * 256;
            kr[i] = *(const bf16x8*)&Kg[(rowbase + (size_t)ktf * 64 + (e >> 4)) * HH + hcol + (e & 15) * 8];
            vr[i] = *(const bf16x8*)&Vt[vtbase + (size_t)(e >> 3) * TT + ktf * 64 + (e & 7) * 8];
        }
    };
    fetch(0);
    int ktmax = 2 * qt + 1;

    for (int kt = 0; kt <= ktmax; kt++) {
        __syncthreads();  // prev iter's Ks/Vs reads complete (and Q hoist on kt=0)
#pragma unroll
        for (int i = 0; i < 4; i++) {
            int e = t + i * 256;
            *(bf16x8*)&Ks[(e >> 4) * 136 + (e & 15) * 8] = kr[i];
            *(bf16x8*)&Vs[(e >> 3) * 72 + (e & 7) * 8]   = vr[i];
        }
        if (kt < ktmax) fetch(kt + 1);
        __syncthreads();

        // S^T: A=K-frag (shared by groups), B=Q-frag
        floatx4 sacc[2][4] = {};
#pragma unroll
        for (int kk = 0; kk < 4; kk++)
#pragma unroll
            for (int jj = 0; jj < 4; jj++) {
                bf16x8 ak = *(const bf16x8*)&Ks[(jj * 16 + cl) * 136 + kk * 32 + quad * 8];
                sacc[0][jj] = __builtin_amdgcn_mfma_f32_16x16x32_bf16(ak, qf[kk][0], sacc[0][jj], 0, 0, 0);
                sacc[1][jj] = __builtin_amdgcn_mfma_f32_16x16x32_bf16(ak, qf[kk][1], sacc[1][jj], 0, 0, 0);
            }

        float p[2][4][4], alpha[2];
        bool diag = (kt >= 2 * qt);
#pragma unroll
        for (int g = 0; g < 2; g++) {
            int qglob = q0 + w * 32 + g * 16 + cl;
            float mx = -1e30f;
#pragma unroll
            for (int jj = 0; jj < 4; jj++)
#pragma unroll
                for (int rg = 0; rg < 4; rg++) {
                    float sv = sacc[g][jj][rg] * scale;
                    if (diag && (kt * 64 + jj * 16 + quad * 4 + rg) > qglob) sv = -1e30f;
                    p[g][jj][rg] = sv;
                    mx = fmaxf(mx, sv);
                }
            mx = fmaxf(mx, __shfl_xor(mx, 16));
            mx = fmaxf(mx, __shfl_xor(mx, 32));
            float mn = fmaxf(m_i[g], mx);
            alpha[g] = __expf(m_i[g] - mn);
            m_i[g] = mn;
            float sum = 0.f;
#pragma unroll
            for (int jj = 0; jj < 4; jj++)
#pragma unroll
                for (int rg = 0; rg < 4; rg++) {
                    float pe = __expf(p[g][jj][rg] - mn);
                    p[g][jj][rg] = pe;
                    sum += pe;
                }
            sum += __shfl_xor(sum, 16);
            sum += __shfl_xor(sum, 32);
            l_i[g] = l_i[g] * alpha[g] + sum;
        }

        int pk[2][4][2];
#pragma unroll
        for (int g = 0; g < 2; g++)
#pragma unroll
            for (int jj = 0; jj < 4; jj++) {
                union { bf16x4 v; int i2[2]; } u;
#pragma unroll
                for (int rg = 0; rg < 4; rg++) u.v[rg] = (bf16)p[g][jj][rg];
                pk[g][jj][0] = u.i2[0];
                pk[g][jj][1] = u.i2[1];
            }
#pragma unroll
        for (int nt = 0; nt < 8; nt++) {
            acc[nt][0] *= alpha[0];
            acc[nt][1] *= alpha[1];
        }

        int La = ((2 * quad) & 3) * 16 + cl;
        int Lb = ((2 * quad + 1) & 3) * 16 + cl;
        bool hi = (quad >> 1) & 1;
#pragma unroll
        for (int kti = 0; kti < 2; kti++) {
            int j0 = kti * 2, j1 = kti * 2 + 1;
            union { bf16x8 v; int i4[4]; } pu[2];
#pragma unroll
            for (int g = 0; g < 2; g++) {
                int a0x = __shfl(pk[g][j0][0], La), a0y = __shfl(pk[g][j0][1], La);
                int a1x = __shfl(pk[g][j1][0], La), a1y = __shfl(pk[g][j1][1], La);
                int b0x = __shfl(pk[g][j0][0], Lb), b0y = __shfl(pk[g][j0][1], Lb);
                int b1x = __shfl(pk[g][j1][0], Lb), b1y = __shfl(pk[g][j1][1], Lb);
                pu[g].i4[0] = hi ? a1x : a0x;
                pu[g].i4[1] = hi ? a1y : a0y;
                pu[g].i4[2] = hi ? b1x : b0x;
                pu[g].i4[3] = hi ? b1y : b0y;
            }
#pragma unroll
            for (int nt = 0; nt < 8; nt++) {
                bf16x8 av = *(const bf16x8*)&Vs[(nt * 16 + cl) * 72 + kti * 32 + quad * 8];
                acc[nt][0] = __builtin_amdgcn_mfma_f32_16x16x32_bf16(av, pu[0].v, acc[nt][0], 0, 0, 0);
                acc[nt][1] = __builtin_amdgcn_mfma_f32_16x16x32_bf16(av, pu[1].v, acc[nt][1], 0, 0, 0);
            }
        }
    }

    float linv[2] = {1.f / l_i[0], 1.f / l_i[1]};
#pragma unroll
    for (int g = 0; g < 2; g++)
#pragma unroll
        for (int nt = 0; nt < 8; nt++) {
            bf16x4 o4;
#pragma unroll
            for (int rg = 0; rg < 4; rg++) o4[rg] = (bf16)(acc[nt][g][rg] * linv[g]);
            *(bf16x4*)&O[(rowbase + q0 + w * 32 + g * 16 + cl) * HH + hcol + nt * 16 + quad * 4] = o4;
        }
}

extern "C" void kernel_launch(void* const* d_in, const int* in_sizes, int n_in,
                              void* d_out, int out_size, void* d_ws, size_t ws_size,
                              hipStream_t stream) {
    const float* x     = (const float*)d_in[0];
    const float* gamma = (const float*)d_in[1];
    const float* beta  = (const float*)d_in[2];
    const float* Wq    = (const float*)d_in[3];
    const float* Wk    = (const float*)d_in[4];
    const float* Wv    = (const float*)d_in[5];
    const float* Wo    = (const float*)d_in[6];
    float* out = (float*)d_out;

    const size_t NELEM = (size_t)MROWS * HH;
    // ws (35.7 MB): Qb bf16 + Vb bf16 + Wslot bf16 (2.1 MB, converted per-GEMM).
    // d_out (33.5 MB f32): Kb bf16 [0,16.8M) + xn bf16 [16.8M,33.5M) — both dead
    // before final GEMM writes d_out. Attention output aliases Qb.
    bf16* Qb    = (bf16*)d_ws;
    bf16* Vb    = Qb + NELEM;          // V^T layout [b][h][d][T]
    bf16* Wslot = Vb + NELEM;
    bf16* Kb    = (bf16*)d_out;
    bf16* xnb   = (bf16*)d_out + NELEM;

    ln_k<<<MROWS, 256, 0, stream>>>(x, gamma, beta, xnb);
    dim3 gg(MROWS / 128, HH / 128);
    convw_k<<<HH * HH / 1024, 256, 0, stream>>>(Wq, Wslot);
    gemm_bf128_k<<<gg, 256, 0, stream>>>(xnb, Wslot, Qb, 0);
    convw_k<<<HH * HH / 1024, 256, 0, stream>>>(Wk, Wslot);
    gemm_bf128_k<<<gg, 256, 0, stream>>>(xnb, Wslot, Kb, 0);
    convw_k<<<HH * HH / 1024, 256, 0, stream>>>(Wv, Wslot);
    gemm_bf128_k<<<gg, 256, 0, stream>>>(xnb, Wslot, Vb, 1);
    attn_k<<<dim3(TT / 128, NHEADS, BB), 256, 0, stream>>>(Qb, Kb, Vb, Qb);
    convw_k<<<HH * HH / 1024, 256, 0, stream>>>(Wo, Wslot);
    gemm_finbf_k<<<gg, 256, 0, stream>>>(Qb, Wslot, x, out);
}

// Round 8
// 342.054 us; speedup vs baseline: 2.2422x; 1.0008x over previous
//
#include <hip/hip_runtime.h>
#include <hip/hip_bf16.h>

#define HH 1024
#define NHEADS 8
#define HDIM 128
#define BB 4
#define TT 2048
#define MROWS (BB*TT)   // 8192

typedef __bf16 bf16;
typedef __bf16 bf16x4 __attribute__((ext_vector_type(4)));
typedef __bf16 bf16x8 __attribute__((ext_vector_type(8)));
typedef float floatx4 __attribute__((ext_vector_type(4)));

// async global->LDS DMA, 16B per lane; lds dest = wave-uniform base + lane*16
__device__ __forceinline__ void gl2lds16(const void* g, void* l) {
    __builtin_amdgcn_global_load_lds(
        (const __attribute__((address_space(1))) unsigned int*)g,
        (__attribute__((address_space(3))) unsigned int*)l, 16, 0, 0);
}

// ---------------- LayerNorm: one block per row, f32 in -> bf16 out ----------------
__global__ __launch_bounds__(256) void ln_k(const float* __restrict__ x,
                                            const float* __restrict__ g,
                                            const float* __restrict__ be,
                                            bf16* __restrict__ xn) {
    int row = blockIdx.x;
    int t = threadIdx.x;
    float4 v4 = ((const float4*)(x + (size_t)row * HH))[t];
    const float* v = (const float*)&v4;
    float s = v[0] + v[1] + v[2] + v[3];
    float s2 = v[0]*v[0] + v[1]*v[1] + v[2]*v[2] + v[3]*v[3];
#pragma unroll
    for (int off = 32; off > 0; off >>= 1) {
        s  += __shfl_down(s,  off);
        s2 += __shfl_down(s2, off);
    }
    __shared__ float red[8];
    if ((t & 63) == 0) { red[t >> 6] = s; red[(t >> 6) + 4] = s2; }
    __syncthreads();
    s  = red[0] + red[1] + red[2] + red[3];
    s2 = red[4] + red[5] + red[6] + red[7];
    float mu  = s * (1.f / HH);
    float var = s2 * (1.f / HH) - mu * mu;
    float rs  = rsqrtf(var + 1e-5f);
    float4 g4 = ((const float4*)g)[t];
    float4 b4 = ((const float4*)be)[t];
    const float* gv = (const float*)&g4;
    const float* bv = (const float*)&b4;
    bf16x4 o;
#pragma unroll
    for (int z = 0; z < 4; z++) o[z] = (bf16)((v[z] - mu) * rs * gv[z] + bv[z]);
    ((bf16x4*)(xn + (size_t)row * HH))[t] = o;
}

// ---------------- Weight convert f32 -> bf16 (1024x1024) ----------------
__global__ __launch_bounds__(256) void convw_k(const float* __restrict__ W,
                                               bf16* __restrict__ Wb) {
    int idx = blockIdx.x * 256 + threadIdx.x;
    float4 v4 = ((const float4*)W)[idx];
    const float* v = (const float*)&v4;
    bf16x4 o;
#pragma unroll
    for (int z = 0; z < 4; z++) o[z] = (bf16)v[z];
    ((bf16x4*)Wb)[idx] = o;
}

// ------- 128x128 bf16 GEMM, m97-style global_load_lds staging -------
// Unpadded 128x32 tiles; source-column swizzle (chunk x ^ ((r>>1)&3)) makes
// frag ds_read_b128 2-way bank-aliased (free). tv=1 -> V^T layout [b][h][d][T].
__global__ __launch_bounds__(256) void gemm_bf128_k(const bf16* __restrict__ A,
                                                    const bf16* __restrict__ W,
                                                    bf16* __restrict__ C, int tv) {
    const int K = HH, N = HH;
    __shared__ __align__(16) bf16 As[128 * 32];
    __shared__ __align__(16) bf16 Ws[128 * 32];
    int m0 = blockIdx.x * 128, n0 = blockIdx.y * 128;
    int t = threadIdx.x, lane = t & 63, w = t >> 6;
    int wm = w >> 1, wn = w & 1;
    int quad = lane >> 4, cl = lane & 15;
    int rA0 = w * 16 + (lane >> 2);                    // + i*64
    int xa = (((lane & 3) ^ ((lane >> 3) & 3)) * 8);   // swizzled source col
    char* AsB = (char*)As + w * 1024;
    char* WsB = (char*)Ws + w * 1024;
    int pc = (quad ^ ((cl >> 1) & 3)) * 8;             // frag phys chunk offset
    floatx4 acc[4][4] = {};
    for (int k0 = 0; k0 < K; k0 += 32) {
        __syncthreads();
#pragma unroll
        for (int i = 0; i < 2; i++) {
            gl2lds16(&A[(size_t)(m0 + rA0 + i * 64) * K + k0 + xa], AsB + i * 4096);
            gl2lds16(&W[(size_t)(n0 + rA0 + i * 64) * K + k0 + xa], WsB + i * 4096);
        }
        __syncthreads();
        bf16x8 af[4], bfr[4];
#pragma unroll
        for (int i = 0; i < 4; i++) af[i]  = *(const bf16x8*)&As[(wm * 64 + i * 16 + cl) * 32 + pc];
#pragma unroll
        for (int j = 0; j < 4; j++) bfr[j] = *(const bf16x8*)&Ws[(wn * 64 + j * 16 + cl) * 32 + pc];
#pragma unroll
        for (int i = 0; i < 4; i++)
#pragma unroll
            for (int j = 0; j < 4; j++)
                acc[i][j] = __builtin_amdgcn_mfma_f32_16x16x32_bf16(af[i], bfr[j], acc[i][j], 0, 0, 0);
    }
#pragma unroll
    for (int i = 0; i < 4; i++)
#pragma unroll
        for (int j = 0; j < 4; j++) {
            int gr = m0 + wm * 64 + i * 16 + quad * 4;
            int gc = n0 + wn * 64 + j * 16 + cl;
            if (!tv) {
#pragma unroll
                for (int rg = 0; rg < 4; rg++)
                    C[(size_t)(gr + rg) * N + gc] = (bf16)acc[i][j][rg];
            } else {
                int bb2 = gr >> 11, tt2 = gr & 2047;
                int hh2 = gc >> 7,  dd2 = gc & 127;
                bf16x4 o4;
#pragma unroll
                for (int rg = 0; rg < 4; rg++) o4[rg] = (bf16)acc[i][j][rg];
                *(bf16x4*)&C[((size_t)(bb2 * NHEADS + hh2) * HDIM + dd2) * TT + tt2] = o4;
            }
        }
}

// ------- 128x128 final GEMM (same staging): out_f32 = A_bf16 * Wb_bf16^T + R_f32 -------
__global__ __launch_bounds__(256) void gemm_finbf_k(const bf16* __restrict__ A,
                                                    const bf16* __restrict__ W,
                                                    const float* __restrict__ R,
                                                    float* __restrict__ C) {
    const int K = HH, N = HH;
    __shared__ __align__(16) bf16 As[128 * 32];
    __shared__ __align__(16) bf16 Ws[128 * 32];
    int m0 = blockIdx.x * 128, n0 = blockIdx.y * 128;
    int t = threadIdx.x, lane = t & 63, w = t >> 6;
    int wm = w >> 1, wn = w & 1;
    int quad = lane >> 4, cl = lane & 15;
    int rA0 = w * 16 + (lane >> 2);
    int xa = (((lane & 3) ^ ((lane >> 3) & 3)) * 8);
    char* AsB = (char*)As + w * 1024;
    char* WsB = (char*)Ws + w * 1024;
    int pc = (quad ^ ((cl >> 1) & 3)) * 8;
    floatx4 acc[4][4] = {};
    for (int k0 = 0; k0 < K; k0 += 32) {
        __syncthreads();
#pragma unroll
        for (int i = 0; i < 2; i++) {
            gl2lds16(&A[(size_t)(m0 + rA0 + i * 64) * K + k0 + xa], AsB + i * 4096);
            gl2lds16(&W[(size_t)(n0 + rA0 + i * 64) * K + k0 + xa], WsB + i * 4096);
        }
        __syncthreads();
        bf16x8 af[4], bfr[4];
#pragma unroll
        for (int i = 0; i < 4; i++) af[i]  = *(const bf16x8*)&As[(wm * 64 + i * 16 + cl) * 32 + pc];
#pragma unroll
        for (int j = 0; j < 4; j++) bfr[j] = *(const bf16x8*)&Ws[(wn * 64 + j * 16 + cl) * 32 + pc];
#pragma unroll
        for (int i = 0; i < 4; i++)
#pragma unroll
            for (int j = 0; j < 4; j++)
                acc[i][j] = __builtin_amdgcn_mfma_f32_16x16x32_bf16(af[i], bfr[j], acc[i][j], 0, 0, 0);
    }
#pragma unroll
    for (int i = 0; i < 4; i++)
#pragma unroll
        for (int j = 0; j < 4; j++)
#pragma unroll
            for (int rg = 0; rg < 4; rg++) {
                int gr = m0 + wm * 64 + i * 16 + quad * 4 + rg;
                int gc = n0 + wn * 64 + j * 16 + cl;
                C[(size_t)gr * N + gc] = acc[i][j][rg] + R[(size_t)gr * N + gc];
            }
}

// ---- Flash attention (causal): 128-row Q tile, Q frags from global, dbuf DMA K/V ----
// Single barrier per kv-tile: DMA for kt+1 issued at top of iter kt into the other
// buffer, drains at the end-of-iter barrier. Unpadded K (64x128) / V (128x64) tiles
// with source-swizzle (K: x^((r>>1)&7), V: x^(r&7)) -> 2-way-aliased frag reads.
// V pre-transposed [b][h][d][T]. O aliases Q (single-owner region per block).
__global__ __launch_bounds__(256) void attn_k(const bf16* __restrict__ Q,
                                              const bf16* __restrict__ Kg,
                                              const bf16* __restrict__ Vt,
                                              bf16* __restrict__ O) {
    __shared__ __align__(16) bf16 Ks2[2][64 * 128];   // 2x16384 B
    __shared__ __align__(16) bf16 Vs2[2][128 * 64];   // 2x16384 B -> 65536 B total

    int qt = gridDim.x - 1 - blockIdx.x;  // longest blocks first
    int h = blockIdx.y, b = blockIdx.z;
    int t = threadIdx.x, lane = t & 63, w = t >> 6;
    int quad = lane >> 4, cl = lane & 15;
    size_t rowbase = (size_t)b * TT;
    int q0 = qt * 128;
    size_t hcol = (size_t)h * HDIM;
    size_t vtbase = (size_t)(b * NHEADS + h) * HDIM * TT;

    // Q fragments straight from global (one-time; L2-warm)
    bf16x8 qf[4][2];
#pragma unroll
    for (int kk = 0; kk < 4; kk++)
#pragma unroll
        for (int g = 0; g < 2; g++)
            qf[kk][g] = *(const bf16x8*)&Q[(rowbase + q0 + w * 32 + g * 16 + cl) * HH + hcol + kk * 32 + quad * 8];

    auto stage = [&](int ktf, int bb) {
        const bf16* kbase = &Kg[(rowbase + (size_t)ktf * 64) * HH + hcol];
        const bf16* vbase = &Vt[vtbase + (size_t)ktf * 64];
#pragma unroll
        for (int i = 0; i < 4; i++) {
            int rk = w * 16 + i * 4 + (lane >> 4);
            int xk = ((lane & 15) ^ ((rk >> 1) & 7)) * 8;
            gl2lds16(kbase + (size_t)rk * HH + xk, (char*)&Ks2[bb][0] + (w * 4 + i) * 1024);
            int rv = w * 32 + i * 8 + (lane >> 3);
            int xv = ((lane & 7) ^ (rv & 7)) * 8;
            gl2lds16(vbase + (size_t)rv * TT + xv, (char*)&Vs2[bb][0] + (w * 4 + i) * 1024);
        }
    };

    float m_i[2] = {-1e30f, -1e30f}, l_i[2] = {0.f, 0.f};
    floatx4 acc[8][2] = {};
    const float scale = 0.08838834764831845f;  // 1/sqrt(128)
    int kswz = ((cl >> 1) & 7);
    int vswz = (cl & 7);

    stage(0, 0);
    int ktmax = 2 * qt + 1;
    int p = 0;
    for (int kt = 0; kt <= ktmax; kt++) {
        if (kt == 0) __syncthreads();          // drain initial DMA
        if (kt < ktmax) stage(kt + 1, p ^ 1);  // in flight across whole body

        // S^T: A = K-frag (shared by both q-groups), B = Q-frag
        floatx4 sacc[2][4] = {};
#pragma unroll
        for (int kk = 0; kk < 4; kk++)
#pragma unroll
            for (int jj = 0; jj < 4; jj++) {
                bf16x8 ak = *(const bf16x8*)&Ks2[p][(jj * 16 + cl) * 128 + ((kk * 4 + quad) ^ kswz) * 8];
                sacc[0][jj] = __builtin_amdgcn_mfma_f32_16x16x32_bf16(ak, qf[kk][0], sacc[0][jj], 0, 0, 0);
                sacc[1][jj] = __builtin_amdgcn_mfma_f32_16x16x32_bf16(ak, qf[kk][1], sacc[1][jj], 0, 0, 0);
            }

        float pp[2][4][4], alpha[2];
        bool diag = (kt >= 2 * qt);
#pragma unroll
        for (int g = 0; g < 2; g++) {
            int qglob = q0 + w * 32 + g * 16 + cl;
            float mx = -1e30f;
#pragma unroll
            for (int jj = 0; jj < 4; jj++)
#pragma unroll
                for (int rg = 0; rg < 4; rg++) {
                    float sv = sacc[g][jj][rg] * scale;
                    if (diag && (kt * 64 + jj * 16 + quad * 4 + rg) > qglob) sv = -1e30f;
                    pp[g][jj][rg] = sv;
                    mx = fmaxf(mx, sv);
                }
            mx = fmaxf(mx, __shfl_xor(mx, 16));
            mx = fmaxf(mx, __shfl_xor(mx, 32));
            float mn = fmaxf(m_i[g], mx);
            alpha[g] = __expf(m_i[g] - mn);
            m_i[g] = mn;
            float sum = 0.f;
#pragma unroll
            for (int jj = 0; jj < 4; jj++)
#pragma unroll
                for (int rg = 0; rg < 4; rg++) {
                    float pe = __expf(pp[g][jj][rg] - mn);
                    pp[g][jj][rg] = pe;
                    sum += pe;
                }
            sum += __shfl_xor(sum, 16);
            sum += __shfl_xor(sum, 32);
            l_i[g] = l_i[g] * alpha[g] + sum;
        }

        int pk[2][4][2];
#pragma unroll
        for (int g = 0; g < 2; g++)
#pragma unroll
            for (int jj = 0; jj < 4; jj++) {
                union { bf16x4 v; int i2[2]; } u;
#pragma unroll
                for (int rg = 0; rg < 4; rg++) u.v[rg] = (bf16)pp[g][jj][rg];
                pk[g][jj][0] = u.i2[0];
                pk[g][jj][1] = u.i2[1];
            }
#pragma unroll
        for (int nt = 0; nt < 8; nt++) {
            acc[nt][0] *= alpha[0];
            acc[nt][1] *= alpha[1];
        }

        int La = ((2 * quad) & 3) * 16 + cl;
        int Lb = ((2 * quad + 1) & 3) * 16 + cl;
        bool hi = (quad >> 1) & 1;
#pragma unroll
        for (int kti = 0; kti < 2; kti++) {
            int j0 = kti * 2, j1 = kti * 2 + 1;
            union { bf16x8 v; int i4[4]; } pu[2];
#pragma unroll
            for (int g = 0; g < 2; g++) {
                int a0x = __shfl(pk[g][j0][0], La), a0y = __shfl(pk[g][j0][1], La);
                int a1x = __shfl(pk[g][j1][0], La), a1y = __shfl(pk[g][j1][1], La);
                int b0x = __shfl(pk[g][j0][0], Lb), b0y = __shfl(pk[g][j0][1], Lb);
                int b1x = __shfl(pk[g][j1][0], Lb), b1y = __shfl(pk[g][j1][1], Lb);
                pu[g].i4[0] = hi ? a1x : a0x;
                pu[g].i4[1] = hi ? a1y : a0y;
                pu[g].i4[2] = hi ? b1x : b0x;
                pu[g].i4[3] = hi ? b1y : b0y;
            }
#pragma unroll
            for (int nt = 0; nt < 8; nt++) {
                bf16x8 av = *(const bf16x8*)&Vs2[p][(nt * 16 + cl) * 64 + ((kti * 4 + quad) ^ vswz) * 8];
                acc[nt][0] = __builtin_amdgcn_mfma_f32_16x16x32_bf16(av, pu[0].v, acc[nt][0], 0, 0, 0);
                acc[nt][1] = __builtin_amdgcn_mfma_f32_16x16x32_bf16(av, pu[1].v, acc[nt][1], 0, 0, 0);
            }
        }
        __syncthreads();   // drains this iter's DMA; all reads of buf p done
        p ^= 1;
    }

    float linv[2] = {1.f / l_i[0], 1.f / l_i[1]};
#pragma unroll
    for (int g = 0; g < 2; g++)
#pragma unroll
        for (int nt = 0; nt < 8; nt++) {
            bf16x4 o4;
#pragma unroll
            for (int rg = 0; rg < 4; rg++) o4[rg] = (bf16)(acc[nt][g][rg] * linv[g]);
            *(bf16x4*)&O[(rowbase + q0 + w * 32 + g * 16 + cl) * HH + hcol + nt * 16 + quad * 4] = o4;
        }
}

extern "C" void kernel_launch(void* const* d_in, const int* in_sizes, int n_in,
                              void* d_out, int out_size, void* d_ws, size_t ws_size,
                              hipStream_t stream) {
    const float* x     = (const float*)d_in[0];
    const float* gamma = (const float*)d_in[1];
    const float* beta  = (const float*)d_in[2];
    const float* Wq    = (const float*)d_in[3];
    const float* Wk    = (const float*)d_in[4];
    const float* Wv    = (const float*)d_in[5];
    const float* Wo    = (const float*)d_in[6];
    float* out = (float*)d_out;

    const size_t NELEM = (size_t)MROWS * HH;
    // ws (35.7 MB): Qb bf16 + Vb bf16 + Wslot bf16 (2.1 MB, converted per-GEMM).
    // d_out (33.5 MB f32): Kb bf16 + xn bf16 — dead before final GEMM writes.
    bf16* Qb    = (bf16*)d_ws;
    bf16* Vb    = Qb + NELEM;          // V^T layout [b][h][d][T]
    bf16* Wslot = Vb + NELEM;
    bf16* Kb    = (bf16*)d_out;
    bf16* xnb   = (bf16*)d_out + NELEM;

    ln_k<<<MROWS, 256, 0, stream>>>(x, gamma, beta, xnb);
    dim3 gg(MROWS / 128, HH / 128);
    convw_k<<<HH * HH / 1024, 256, 0, stream>>>(Wq, Wslot);
    gemm_bf128_k<<<gg, 256, 0, stream>>>(xnb, Wslot, Qb, 0);
    convw_k<<<HH * HH / 1024, 256, 0, stream>>>(Wk, Wslot);
    gemm_bf128_k<<<gg, 256, 0, stream>>>(xnb, Wslot, Kb, 0);
    convw_k<<<HH * HH / 1024, 256, 0, stream>>>(Wv, Wslot);
    gemm_bf128_k<<<gg, 256, 0, stream>>>(xnb, Wslot, Vb, 1);
    attn_k<<<dim3(TT / 128, NHEADS, BB), 256, 0, stream>>>(Qb, Kb, Vb, Qb);
    convw_k<<<HH * HH / 1024, 256, 0, stream>>>(Wo, Wslot);
    gemm_finbf_k<<<gg, 256, 0, stream>>>(Qb, Wslot, x, out);
}